// Round 3
// baseline (1118.647 us; speedup 1.0000x reference)
//
#include <hip/hip_runtime.h>
#include <cstddef>

#define NROWS 16384
#define NCOLS 4096
#define NG 32
#define GD 128
#define NPC 16              // cov partials per group
#define NPB 512             // pack blocks

typedef float f32x4 __attribute__((ext_vector_type(4)));
typedef short bf16x8 __attribute__((ext_vector_type(8)));

__device__ inline unsigned short f2bf(float f) {
    unsigned int u = __builtin_bit_cast(unsigned int, f);
    u += 0x7fffu + ((u >> 16) & 1u);
    return (unsigned short)(u >> 16);
}

// ============ K0: pack x -> per-group bf16 copy + partial column sums =========
// grid 512 x 256 thr; block = 32 consecutive rows (512 KB contiguous read).
__global__ __launch_bounds__(256) void k_pack(
    const float* __restrict__ x, unsigned short* __restrict__ xhi,
    float* __restrict__ ps)
{
    const int b = blockIdx.x;
    const int t = threadIdx.x;
    const int r0 = b * 32;
    float cs[16];
#pragma unroll
    for (int j = 0; j < 16; ++j) cs[j] = 0.f;

    for (int r = 0; r < 32; ++r) {
        const float* xr = x + (size_t)(r0 + r) * NCOLS;
#pragma unroll
        for (int j4 = 0; j4 < 4; ++j4) {
            const int c = j4 * 1024 + 4 * t;
            float4 v = *(const float4*)(xr + c);
            cs[j4 * 4 + 0] += v.x; cs[j4 * 4 + 1] += v.y;
            cs[j4 * 4 + 2] += v.z; cs[j4 * 4 + 3] += v.w;
            ushort4 h;
            h.x = f2bf(v.x); h.y = f2bf(v.y); h.z = f2bf(v.z); h.w = f2bf(v.w);
            const int g = c >> 7, d = c & 127;
            *(ushort4*)(xhi + ((size_t)g * NROWS + (r0 + r)) * GD + d) = h;
        }
    }
#pragma unroll
    for (int j4 = 0; j4 < 4; ++j4) {
        const int c = j4 * 1024 + 4 * t;
        *(float4*)(ps + (size_t)b * NCOLS + c) =
            make_float4(cs[j4 * 4 + 0], cs[j4 * 4 + 1], cs[j4 * 4 + 2], cs[j4 * 4 + 3]);
    }
}

// ============ K0b: reduce partial colsums -> mean ==============================
__global__ __launch_bounds__(256) void k_mean(
    const float* __restrict__ ps, float* __restrict__ mean)
{
    const int col = blockIdx.x * 256 + threadIdx.x;
    float s = 0.f;
    for (int b = 0; b < NPB; ++b) s += ps[(size_t)b * NCOLS + col];
    mean[col] = s * (1.0f / (float)NROWS);
}

// ============ K1: bf16 MFMA partial X^T X from packed xhi =====================
// grid 512 = 32 groups x 16 stripes; 256 thr; 1024 rows/block, contiguous.
__global__ __launch_bounds__(256) void k_cov(
    const unsigned short* __restrict__ xhi, float* __restrict__ xtx)
{
    __shared__ unsigned short xt[2][128][40];   // [feat][k-row] bf16, 80B rows
    const int bid = blockIdx.x;
    const int g = bid >> 4, p = bid & 15;
    const int t = threadIdx.x;
    const int f2 = t & 63;          // feature pair
    const int rh = t >> 6;          // wave id = row-eighth
    const int w = rh;
    const int lane = t & 63;
    const int lm = lane & 15, lk = lane >> 4;
    const unsigned short* xb = xhi + ((size_t)g * NROWS + p * 1024) * GD + 2 * f2;

    f32x4 acc[2][8];
#pragma unroll
    for (int mi = 0; mi < 2; ++mi)
#pragma unroll
        for (int ni = 0; ni < 8; ++ni) acc[mi][ni] = (f32x4){0.f, 0.f, 0.f, 0.f};

    ushort2 v[8];
#define CLOAD(CC) \
    _Pragma("unroll") for (int i = 0; i < 8; ++i) \
        v[i] = *(const ushort2*)(xb + (size_t)((CC) * 32 + rh * 8 + i) * GD);
#define CWRITE(BUF) { \
    bf16x8 h0, h1; \
    _Pragma("unroll") for (int i = 0; i < 8; ++i) { \
        h0[i] = (short)v[i].x; h1[i] = (short)v[i].y; } \
    *(bf16x8*)&xt[BUF][2 * f2][rh * 8] = h0; \
    *(bf16x8*)&xt[BUF][2 * f2 + 1][rh * 8] = h1; }

    CLOAD(0);
    CWRITE(0);
    __syncthreads();

    for (int c = 0; c < 32; ++c) {
        const int cur = c & 1;
        if (c < 31) { CLOAD(c + 1); }
        bf16x8 frag[8];
#pragma unroll
        for (int fb = 0; fb < 8; ++fb)
            frag[fb] = *(const bf16x8*)&xt[cur][fb * 16 + lm][lk * 8];
#pragma unroll
        for (int mi = 0; mi < 2; ++mi)
#pragma unroll
            for (int ni = 0; ni < 8; ++ni)
                acc[mi][ni] = __builtin_amdgcn_mfma_f32_16x16x32_bf16(
                    frag[w * 2 + mi], frag[ni], acc[mi][ni], 0, 0, 0);
        if (c < 31) { CWRITE(cur ^ 1); }
        __syncthreads();
    }
#undef CLOAD
#undef CWRITE

    float* ob = xtx + (size_t)bid * (GD * GD);
#pragma unroll
    for (int mi = 0; mi < 2; ++mi)
#pragma unroll
        for (int ni = 0; ni < 8; ++ni) {
            const int i0 = (w * 2 + mi) * 16 + lk * 4;
            const int j = ni * 16 + lm;
#pragma unroll
            for (int r = 0; r < 4; ++r)
                ob[(size_t)(i0 + r) * GD + j] = acc[mi][ni][r];
        }
}

// ============ K2: reduce partials -> C (mean-corrected) =======================
__global__ __launch_bounds__(256) void k_covreduce(
    const float* __restrict__ xtx, const float* __restrict__ mean,
    float* __restrict__ C)
{
    __shared__ float mu[128];
    const int bid = blockIdx.x;
    const int g = bid >> 4, s = bid & 15;
    const int t = threadIdx.x;
    if (t < 128) mu[t] = mean[g * GD + t];
    __syncthreads();
    const int e = s * 1024 + t * 4;
    const int i = e >> 7, j = e & 127;
    float4 sum = make_float4(0.f, 0.f, 0.f, 0.f);
#pragma unroll
    for (int p = 0; p < NPC; ++p) {
        const float4 vv = *(const float4*)(xtx + ((size_t)(g * NPC + p) << 14) + e);
        sum.x += vv.x; sum.y += vv.y; sum.z += vv.z; sum.w += vv.w;
    }
    const float inv = 1.0f / (float)(NROWS - 1);
    const float mi2 = (float)NROWS * mu[i];
    float4 r;
    r.x = (sum.x - mi2 * mu[j + 0]) * inv;
    r.y = (sum.y - mi2 * mu[j + 1]) * inv;
    r.z = (sum.z - mi2 * mu[j + 2]) * inv;
    r.w = (sum.w - mi2 * mu[j + 3]) * inv;
    *(float4*)(C + (size_t)g * (GD * GD) + e) = r;
}

// ============ K3: Gershgorin scale + Y0/Z0 ====================================
__global__ __launch_bounds__(256) void k_prep(
    const float* __restrict__ Cg, float* __restrict__ scale,
    float* __restrict__ Y0, float* __restrict__ Z0)
{
    __shared__ float Cs[128][129];
    __shared__ float rs[128];
    __shared__ float sinv[1];
    const int g = blockIdx.x;
    const int t = threadIdx.x;
    for (int k = 0; k < 64; ++k) {
        int e = t + 256 * k;
        Cs[e >> 7][e & 127] = Cg[(size_t)g * (GD * GD) + e];
    }
    __syncthreads();
    if (t < 128) {
        float s = 0.f;
        for (int i = 0; i < 128; ++i) s += fabsf(Cs[i][t]);
        rs[t] = s;
    }
    __syncthreads();
    if (t == 0) {
        float up = 0.f, lo = 1e30f;
        for (int i = 0; i < 128; ++i) {
            up = fmaxf(up, rs[i]);
            lo = fminf(lo, 2.0f * Cs[i][i] - rs[i]);
        }
        float c = 0.5f * (up + fmaxf(lo, 0.0f));
        c = fmaxf(c, 1e-20f);
        sinv[0] = 1.0f / c;
        scale[g] = rsqrtf(c);
    }
    __syncthreads();
    const float invc = sinv[0];
    for (int k = 0; k < 64; ++k) {
        int e = t + 256 * k;
        int i = e >> 7, j = e & 127;
        Y0[(size_t)g * (GD * GD) + e] = Cs[i][j] * invc;
        Z0[(size_t)g * (GD * GD) + e] = (i == j) ? 1.0f : 0.0f;
    }
}

// ============ K4: Newton-Schulz iteration (fp32) ==============================
__global__ __launch_bounds__(256) void k_ns_iter(
    const float* __restrict__ Yin, const float* __restrict__ Zin,
    float* __restrict__ Yout, float* __restrict__ Zout)
{
    __shared__ float Ys[128][132];
    __shared__ float Zs[128][132];
    __shared__ float Ts[128][16];
    const int bid = blockIdx.x;
    const int g = bid >> 3;
    const int sl = bid & 7;
    const int J0 = sl * 16;
    const int t = threadIdx.x;
    const float* Yg = Yin + (size_t)g * GD * GD;
    const float* Zg = Zin + (size_t)g * GD * GD;
#pragma unroll
    for (int k = 0; k < 16; ++k) {
        int q = t + 256 * k;
        int row = q >> 5, c4 = q & 31;
        *(float4*)&Ys[row][c4 * 4] = *(const float4*)(Yg + (size_t)q * 4);
        *(float4*)&Zs[row][c4 * 4] = *(const float4*)(Zg + (size_t)q * 4);
    }
    __syncthreads();
    const int i = t >> 1;
    const int jb = (t & 1) * 8;

    float accT[8];
#pragma unroll
    for (int q = 0; q < 8; ++q) accT[q] = 0.f;
    for (int k4 = 0; k4 < 32; ++k4) {
        float4 zv = *(const float4*)&Zs[i][k4 * 4];
        float zz[4] = {zv.x, zv.y, zv.z, zv.w};
#pragma unroll
        for (int e = 0; e < 4; ++e) {
            const int k = k4 * 4 + e;
            float4 y0 = *(const float4*)&Ys[k][J0 + jb];
            float4 y1 = *(const float4*)&Ys[k][J0 + jb + 4];
            float yy[8] = {y0.x, y0.y, y0.z, y0.w, y1.x, y1.y, y1.z, y1.w};
#pragma unroll
            for (int q = 0; q < 8; ++q) accT[q] = fmaf(zz[e], yy[q], accT[q]);
        }
    }
#pragma unroll
    for (int q = 0; q < 8; ++q) Ts[i][jb + q] = accT[q];
    __syncthreads();

    float ay[8], az[8];
#pragma unroll
    for (int q = 0; q < 8; ++q) { ay[q] = 0.f; az[q] = 0.f; }
    for (int k4 = 0; k4 < 32; ++k4) {
        float4 yv = *(const float4*)&Ys[i][k4 * 4];
        float4 zv = *(const float4*)&Zs[i][k4 * 4];
        float yy[4] = {yv.x, yv.y, yv.z, yv.w};
        float zz[4] = {zv.x, zv.y, zv.z, zv.w};
#pragma unroll
        for (int e = 0; e < 4; ++e) {
            const int k = k4 * 4 + e;
            float4 t0 = *(const float4*)&Ts[k][jb];
            float4 t1 = *(const float4*)&Ts[k][jb + 4];
            float tt[8] = {t0.x, t0.y, t0.z, t0.w, t1.x, t1.y, t1.z, t1.w};
#pragma unroll
            for (int q = 0; q < 8; ++q) {
                ay[q] = fmaf(yy[e], tt[q], ay[q]);
                az[q] = fmaf(zz[e], tt[q], az[q]);
            }
        }
    }
    float4 yc0 = *(const float4*)&Ys[i][J0 + jb];
    float4 yc1 = *(const float4*)&Ys[i][J0 + jb + 4];
    float4 zc0 = *(const float4*)&Zs[i][J0 + jb];
    float4 zc1 = *(const float4*)&Zs[i][J0 + jb + 4];
    float* Yo = Yout + (size_t)g * GD * GD + (size_t)i * GD + J0 + jb;
    float* Zo = Zout + (size_t)g * GD * GD + (size_t)i * GD + J0 + jb;
    *(float4*)(Yo)     = make_float4(1.5f*yc0.x - 0.5f*ay[0], 1.5f*yc0.y - 0.5f*ay[1],
                                     1.5f*yc0.z - 0.5f*ay[2], 1.5f*yc0.w - 0.5f*ay[3]);
    *(float4*)(Yo + 4) = make_float4(1.5f*yc1.x - 0.5f*ay[4], 1.5f*yc1.y - 0.5f*ay[5],
                                     1.5f*yc1.z - 0.5f*ay[6], 1.5f*yc1.w - 0.5f*ay[7]);
    *(float4*)(Zo)     = make_float4(1.5f*zc0.x - 0.5f*az[0], 1.5f*zc0.y - 0.5f*az[1],
                                     1.5f*zc0.z - 0.5f*az[2], 1.5f*zc0.w - 0.5f*az[3]);
    *(float4*)(Zo + 4) = make_float4(1.5f*zc1.x - 0.5f*az[4], 1.5f*zc1.y - 0.5f*az[5],
                                     1.5f*zc1.z - 0.5f*az[6], 1.5f*zc1.w - 0.5f*az[7]);
}

// ============ K5: WT = (Z*rsqrt(c))^T bf16 ; muW = mu . W =====================
__global__ __launch_bounds__(256) void k_wprep(
    const float* __restrict__ Z, const float* __restrict__ scale,
    const float* __restrict__ mean,
    unsigned short* __restrict__ WT, float* __restrict__ muW)
{
    __shared__ float Zs[128][129];
    __shared__ float mu[128];
    const int g = blockIdx.x;
    const int t = threadIdx.x;
    const float sc = scale[g];
    if (t < 128) mu[t] = mean[g * GD + t];
    for (int k = 0; k < 64; ++k) {
        int e = t + 256 * k;
        Zs[e >> 7][e & 127] = Z[(size_t)g * (GD * GD) + e];
    }
    __syncthreads();
    const int n = t & 127, kh = t >> 7;
    unsigned short* o = WT + (size_t)g * (GD * GD) + (size_t)n * GD + kh * 64;
    for (int k = 0; k < 64; k += 2) {
        unsigned int pk = (unsigned int)f2bf(Zs[kh * 64 + k][n] * sc)
                        | ((unsigned int)f2bf(Zs[kh * 64 + k + 1][n] * sc) << 16);
        *(unsigned int*)(o + k) = pk;
    }
    if (t < 128) {
        float s = 0.f;
        for (int d = 0; d < 128; ++d) s = fmaf(mu[d], Zs[d][t], s);
        muW[g * GD + t] = s * sc;
    }
}

// ============ K6: out = xhi * W - muW  (no LDS, A-frags direct from global) ===
// grid 8192 = 32 groups x 256 row-blocks (64 rows each); 256 thr (4 waves).
__global__ __launch_bounds__(256) void k_apply(
    const unsigned short* __restrict__ xhi, const unsigned short* __restrict__ WT,
    const float* __restrict__ muW, float* __restrict__ out)
{
    const int bid = blockIdx.x;
    const int g = bid >> 8, rb = bid & 255;
    const int t = threadIdx.x;
    const int lane = t & 63, w = t >> 6;
    const int lm = lane & 15, lk = lane >> 4;
    const int nh = w >> 1;              // n-half (64 cols)
    const int m0w = (w & 1) * 32;       // row offset within 64-row block
    const int row0 = rb * 64;

    bf16x8 Wf[4][4];
    {
        const unsigned short* wg = WT + (size_t)g * (GD * GD);
#pragma unroll
        for (int ni = 0; ni < 4; ++ni)
#pragma unroll
            for (int ks = 0; ks < 4; ++ks)
                Wf[ni][ks] = *(const bf16x8*)(wg
                    + (size_t)(nh * 64 + ni * 16 + lm) * GD + ks * 32 + lk * 8);
    }
    const unsigned short* ab = xhi + ((size_t)g * NROWS + row0 + m0w) * GD;

    f32x4 acc[2][4];
#pragma unroll
    for (int mi = 0; mi < 2; ++mi)
#pragma unroll
        for (int ni = 0; ni < 4; ++ni) acc[mi][ni] = (f32x4){0.f, 0.f, 0.f, 0.f};

#pragma unroll
    for (int ks = 0; ks < 4; ++ks) {
        bf16x8 a0 = *(const bf16x8*)(ab + (size_t)lm * GD + ks * 32 + lk * 8);
        bf16x8 a1 = *(const bf16x8*)(ab + (size_t)(16 + lm) * GD + ks * 32 + lk * 8);
#pragma unroll
        for (int ni = 0; ni < 4; ++ni) {
            acc[0][ni] = __builtin_amdgcn_mfma_f32_16x16x32_bf16(
                a0, Wf[ni][ks], acc[0][ni], 0, 0, 0);
            acc[1][ni] = __builtin_amdgcn_mfma_f32_16x16x32_bf16(
                a1, Wf[ni][ks], acc[1][ni], 0, 0, 0);
        }
    }
    const float* mg = muW + g * GD;
    float mw[4];
#pragma unroll
    for (int ni = 0; ni < 4; ++ni) mw[ni] = mg[nh * 64 + ni * 16 + lm];

    float* ob = out + (size_t)(row0 + m0w) * NCOLS + g * GD + nh * 64;
#pragma unroll
    for (int mi = 0; mi < 2; ++mi)
#pragma unroll
        for (int ni = 0; ni < 4; ++ni)
#pragma unroll
            for (int r = 0; r < 4; ++r)
                ob[(size_t)(mi * 16 + lk * 4 + r) * NCOLS + ni * 16 + lm]
                    = acc[mi][ni][r] - mw[ni];
}

extern "C" void kernel_launch(void* const* d_in, const int* in_sizes, int n_in,
                              void* d_out, int out_size, void* d_ws, size_t ws_size,
                              hipStream_t stream) {
    const float* x = (const float*)d_in[0];
    float* out = (float*)d_out;
    float* ws = (float*)d_ws;

    float* xtx   = ws;                                    // 512*16384   = 8,388,608
    float* ps    = xtx + (size_t)NG * NPC * GD * GD;      // 512*4096    = 2,097,152
    float* mean  = ps + (size_t)NPB * NCOLS;              // 4,096
    float* scale = mean + NCOLS;                          // 32
    float* Cbuf  = scale + 32;                            // 524,288
    float* Ya    = Cbuf + (size_t)NG * GD * GD;
    float* Za    = Ya + (size_t)NG * GD * GD;
    float* Yb    = Za + (size_t)NG * GD * GD;
    float* Zb    = Yb + (size_t)NG * GD * GD;
    float* muW   = Zb + (size_t)NG * GD * GD;             // 4,096
    unsigned short* WT  = (unsigned short*)(muW + NCOLS); // 2,097,152 shorts
    unsigned short* xhi = WT + (size_t)NG * GD * GD;      // 33,554,432 shorts

    k_pack<<<NPB, 256, 0, stream>>>(x, xhi, ps);
    k_mean<<<NCOLS / 256, 256, 0, stream>>>(ps, mean);
    k_cov<<<NG * NPC, 256, 0, stream>>>(xhi, xtx);
    k_covreduce<<<NG * NPC, 256, 0, stream>>>(xtx, mean, Cbuf);
    k_prep<<<NG, 256, 0, stream>>>(Cbuf, scale, Ya, Za);
    for (int it = 0; it < 6; ++it) {
        if ((it & 1) == 0)
            k_ns_iter<<<NG * 8, 256, 0, stream>>>(Ya, Za, Yb, Zb);
        else
            k_ns_iter<<<NG * 8, 256, 0, stream>>>(Yb, Zb, Ya, Za);
    }
    k_wprep<<<NG, 256, 0, stream>>>(Za, scale, mean, WT, muW);
    k_apply<<<NG * 256, 256, 0, stream>>>(xhi, WT, muW, out);
}

// Round 4
// 711.308 us; speedup vs baseline: 1.5727x; 1.5727x over previous
//
#include <hip/hip_runtime.h>
#include <cstddef>

#define NROWS 16384
#define NCOLS 4096
#define NG 32
#define GD 128
#define NPC 16              // K-stripes (1024 samples each)
#define NPB 512             // pack blocks (32 samples each)

typedef float f32x4 __attribute__((ext_vector_type(4)));
typedef short bf16x8 __attribute__((ext_vector_type(8)));

__device__ inline unsigned short f2bf(float f) {
    unsigned int u = __builtin_bit_cast(unsigned int, f);
    u += 0x7fffu + ((u >> 16) & 1u);
    return (unsigned short)(u >> 16);
}

// ============ K0: pack x -> transposed bf16 xT[g*16+p][d][1024] + col partials =
// grid 512 x 256 thr; block = 32 consecutive samples.
__global__ __launch_bounds__(256) void k_pack(
    const float* __restrict__ x, unsigned short* __restrict__ xT,
    float* __restrict__ ps)
{
    __shared__ unsigned short tT[128][40];   // [feat][sample] bf16, 80 B rows
    const int b = blockIdx.x;
    const int p = b >> 5;            // K-stripe
    const int r0l = (b & 31) * 32;   // sample offset within stripe
    const int r0 = b * 32;           // global sample
    const int t = threadIdx.x;
    const int r = t >> 3;            // 0..31
    const int c0 = (t & 7) * 4;
    const int d = t >> 1, hf = t & 1;

    for (int g = 0; g < NG; ++g) {
        __syncthreads();
#pragma unroll
        for (int j = 0; j < 4; ++j) {
            const int c = c0 + 32 * j;
            float4 v = *(const float4*)(x + (size_t)(r0 + r) * NCOLS + g * GD + c);
            tT[c + 0][r] = f2bf(v.x);
            tT[c + 1][r] = f2bf(v.y);
            tT[c + 2][r] = f2bf(v.z);
            tT[c + 3][r] = f2bf(v.w);
        }
        __syncthreads();
        // transposed write: thread -> feature d, 16 samples (hf half)
        uint4 q0 = *(const uint4*)&tT[d][hf * 16];
        uint4 q1 = *(const uint4*)&tT[d][hf * 16 + 8];
        unsigned short* o = xT + ((size_t)(g * NPC + p) * GD + d) * 1024 + r0l + hf * 16;
        *(uint4*)(o) = q0;
        *(uint4*)(o + 8) = q1;
        // column partial sums (32 samples) from the bf16 values
        float s = 0.f;
        {
            unsigned int ws[8] = {q0.x, q0.y, q0.z, q0.w, q1.x, q1.y, q1.z, q1.w};
#pragma unroll
            for (int i = 0; i < 8; ++i) {
                s += __builtin_bit_cast(float, ws[i] << 16);
                s += __builtin_bit_cast(float, ws[i] & 0xffff0000u);
            }
        }
        s += __shfl_xor(s, 1);
        if (hf == 0) ps[(size_t)b * NCOLS + g * GD + d] = s;
    }
}

// ============ K0b: reduce partial colsums -> mean ==============================
__global__ __launch_bounds__(256) void k_mean(
    const float* __restrict__ ps, float* __restrict__ mean)
{
    const int col = blockIdx.x * 256 + threadIdx.x;
    float s0 = 0.f, s1 = 0.f, s2 = 0.f, s3 = 0.f;
    for (int b = 0; b < NPB; b += 4) {
        s0 += ps[(size_t)(b + 0) * NCOLS + col];
        s1 += ps[(size_t)(b + 1) * NCOLS + col];
        s2 += ps[(size_t)(b + 2) * NCOLS + col];
        s3 += ps[(size_t)(b + 3) * NCOLS + col];
    }
    mean[col] = (s0 + s1 + s2 + s3) * (1.0f / (float)NROWS);
}

// ============ K1: register-only MFMA partial X^T X from xT ====================
// grid 512 = 32 g x 16 stripes; 256 thr (4 waves); no LDS.
__global__ __launch_bounds__(256) void k_cov(
    const unsigned short* __restrict__ xT, float* __restrict__ xtx)
{
    const int bid = blockIdx.x;
    const int t = threadIdx.x;
    const int w = t >> 6, lane = t & 63;
    const int lm = lane & 15, lk = lane >> 4;
    // lane's fragment pointer: row lm (+16n), k-chunk lk*8 (+32*ks)
    const unsigned short* lp = xT + ((size_t)bid * GD + lm) * 1024 + lk * 8;

    f32x4 acc[2][8];
#pragma unroll
    for (int mi = 0; mi < 2; ++mi)
#pragma unroll
        for (int ni = 0; ni < 8; ++ni) acc[mi][ni] = (f32x4){0.f, 0.f, 0.f, 0.f};

    bf16x8 bA[8], bB[8];
#pragma unroll
    for (int n = 0; n < 8; ++n) bA[n] = *(const bf16x8*)(lp + n * 16 * 1024);

    for (int ks = 0; ks < 32; ks += 2) {
        const unsigned short* nx = lp + (ks + 1) * 32;
#pragma unroll
        for (int n = 0; n < 8; ++n) bB[n] = *(const bf16x8*)(nx + n * 16 * 1024);
#pragma unroll
        for (int mi = 0; mi < 2; ++mi)
#pragma unroll
            for (int ni = 0; ni < 8; ++ni)
                acc[mi][ni] = __builtin_amdgcn_mfma_f32_16x16x32_bf16(
                    bA[w * 2 + mi], bA[ni], acc[mi][ni], 0, 0, 0);
        const unsigned short* nx2 = lp + ((ks + 2 < 32) ? (ks + 2) * 32 : 0);
#pragma unroll
        for (int n = 0; n < 8; ++n) bA[n] = *(const bf16x8*)(nx2 + n * 16 * 1024);
#pragma unroll
        for (int mi = 0; mi < 2; ++mi)
#pragma unroll
            for (int ni = 0; ni < 8; ++ni)
                acc[mi][ni] = __builtin_amdgcn_mfma_f32_16x16x32_bf16(
                    bB[w * 2 + mi], bB[ni], acc[mi][ni], 0, 0, 0);
    }

    float* ob = xtx + (size_t)bid * (GD * GD);
#pragma unroll
    for (int mi = 0; mi < 2; ++mi)
#pragma unroll
        for (int ni = 0; ni < 8; ++ni) {
            const int i0 = (w * 2 + mi) * 16 + lk * 4;
            const int j = ni * 16 + lm;
#pragma unroll
            for (int r = 0; r < 4; ++r)
                ob[(size_t)(i0 + r) * GD + j] = acc[mi][ni][r];
        }
}

// ============ K2: reduce partials -> C (mean-corrected) =======================
__global__ __launch_bounds__(256) void k_covreduce(
    const float* __restrict__ xtx, const float* __restrict__ mean,
    float* __restrict__ C)
{
    __shared__ float mu[128];
    const int bid = blockIdx.x;
    const int g = bid >> 4, s = bid & 15;
    const int t = threadIdx.x;
    if (t < 128) mu[t] = mean[g * GD + t];
    __syncthreads();
    const int e = s * 1024 + t * 4;
    const int i = e >> 7, j = e & 127;
    float4 sum = make_float4(0.f, 0.f, 0.f, 0.f);
#pragma unroll
    for (int p = 0; p < NPC; ++p) {
        const float4 vv = *(const float4*)(xtx + ((size_t)(g * NPC + p) << 14) + e);
        sum.x += vv.x; sum.y += vv.y; sum.z += vv.z; sum.w += vv.w;
    }
    const float inv = 1.0f / (float)(NROWS - 1);
    const float mi2 = (float)NROWS * mu[i];
    float4 r;
    r.x = (sum.x - mi2 * mu[j + 0]) * inv;
    r.y = (sum.y - mi2 * mu[j + 1]) * inv;
    r.z = (sum.z - mi2 * mu[j + 2]) * inv;
    r.w = (sum.w - mi2 * mu[j + 3]) * inv;
    *(float4*)(C + (size_t)g * (GD * GD) + e) = r;
}

// ============ K3: Gershgorin scale + Y0/Z0 ====================================
__global__ __launch_bounds__(256) void k_prep(
    const float* __restrict__ Cg, float* __restrict__ scale,
    float* __restrict__ Y0, float* __restrict__ Z0)
{
    __shared__ float Cs[128][129];
    __shared__ float rs[128];
    __shared__ float sinv[1];
    const int g = blockIdx.x;
    const int t = threadIdx.x;
    for (int k = 0; k < 64; ++k) {
        int e = t + 256 * k;
        Cs[e >> 7][e & 127] = Cg[(size_t)g * (GD * GD) + e];
    }
    __syncthreads();
    if (t < 128) {
        float s = 0.f;
        for (int i = 0; i < 128; ++i) s += fabsf(Cs[i][t]);
        rs[t] = s;
    }
    __syncthreads();
    if (t == 0) {
        float up = 0.f, lo = 1e30f;
        for (int i = 0; i < 128; ++i) {
            up = fmaxf(up, rs[i]);
            lo = fminf(lo, 2.0f * Cs[i][i] - rs[i]);
        }
        float c = 0.5f * (up + fmaxf(lo, 0.0f));
        c = fmaxf(c, 1e-20f);
        sinv[0] = 1.0f / c;
        scale[g] = rsqrtf(c);
    }
    __syncthreads();
    const float invc = sinv[0];
    for (int k = 0; k < 64; ++k) {
        int e = t + 256 * k;
        int i = e >> 7, j = e & 127;
        Y0[(size_t)g * (GD * GD) + e] = Cs[i][j] * invc;
        Z0[(size_t)g * (GD * GD) + e] = (i == j) ? 1.0f : 0.0f;
    }
}

// ============ K4: Newton-Schulz iteration (fp32) ==============================
__global__ __launch_bounds__(256) void k_ns_iter(
    const float* __restrict__ Yin, const float* __restrict__ Zin,
    float* __restrict__ Yout, float* __restrict__ Zout)
{
    __shared__ float Ys[128][132];
    __shared__ float Zs[128][132];
    __shared__ float Ts[128][16];
    const int bid = blockIdx.x;
    const int g = bid >> 3;
    const int sl = bid & 7;
    const int J0 = sl * 16;
    const int t = threadIdx.x;
    const float* Yg = Yin + (size_t)g * GD * GD;
    const float* Zg = Zin + (size_t)g * GD * GD;
#pragma unroll
    for (int k = 0; k < 16; ++k) {
        int q = t + 256 * k;
        int row = q >> 5, c4 = q & 31;
        *(float4*)&Ys[row][c4 * 4] = *(const float4*)(Yg + (size_t)q * 4);
        *(float4*)&Zs[row][c4 * 4] = *(const float4*)(Zg + (size_t)q * 4);
    }
    __syncthreads();
    const int i = t >> 1;
    const int jb = (t & 1) * 8;

    float accT[8];
#pragma unroll
    for (int q = 0; q < 8; ++q) accT[q] = 0.f;
    for (int k4 = 0; k4 < 32; ++k4) {
        float4 zv = *(const float4*)&Zs[i][k4 * 4];
        float zz[4] = {zv.x, zv.y, zv.z, zv.w};
#pragma unroll
        for (int e = 0; e < 4; ++e) {
            const int k = k4 * 4 + e;
            float4 y0 = *(const float4*)&Ys[k][J0 + jb];
            float4 y1 = *(const float4*)&Ys[k][J0 + jb + 4];
            float yy[8] = {y0.x, y0.y, y0.z, y0.w, y1.x, y1.y, y1.z, y1.w};
#pragma unroll
            for (int q = 0; q < 8; ++q) accT[q] = fmaf(zz[e], yy[q], accT[q]);
        }
    }
#pragma unroll
    for (int q = 0; q < 8; ++q) Ts[i][jb + q] = accT[q];
    __syncthreads();

    float ay[8], az[8];
#pragma unroll
    for (int q = 0; q < 8; ++q) { ay[q] = 0.f; az[q] = 0.f; }
    for (int k4 = 0; k4 < 32; ++k4) {
        float4 yv = *(const float4*)&Ys[i][k4 * 4];
        float4 zv = *(const float4*)&Zs[i][k4 * 4];
        float yy[4] = {yv.x, yv.y, yv.z, yv.w};
        float zz[4] = {zv.x, zv.y, zv.z, zv.w};
#pragma unroll
        for (int e = 0; e < 4; ++e) {
            const int k = k4 * 4 + e;
            float4 t0 = *(const float4*)&Ts[k][jb];
            float4 t1 = *(const float4*)&Ts[k][jb + 4];
            float tt[8] = {t0.x, t0.y, t0.z, t0.w, t1.x, t1.y, t1.z, t1.w};
#pragma unroll
            for (int q = 0; q < 8; ++q) {
                ay[q] = fmaf(yy[e], tt[q], ay[q]);
                az[q] = fmaf(zz[e], tt[q], az[q]);
            }
        }
    }
    float4 yc0 = *(const float4*)&Ys[i][J0 + jb];
    float4 yc1 = *(const float4*)&Ys[i][J0 + jb + 4];
    float4 zc0 = *(const float4*)&Zs[i][J0 + jb];
    float4 zc1 = *(const float4*)&Zs[i][J0 + jb + 4];
    float* Yo = Yout + (size_t)g * GD * GD + (size_t)i * GD + J0 + jb;
    float* Zo = Zout + (size_t)g * GD * GD + (size_t)i * GD + J0 + jb;
    *(float4*)(Yo)     = make_float4(1.5f*yc0.x - 0.5f*ay[0], 1.5f*yc0.y - 0.5f*ay[1],
                                     1.5f*yc0.z - 0.5f*ay[2], 1.5f*yc0.w - 0.5f*ay[3]);
    *(float4*)(Yo + 4) = make_float4(1.5f*yc1.x - 0.5f*ay[4], 1.5f*yc1.y - 0.5f*ay[5],
                                     1.5f*yc1.z - 0.5f*ay[6], 1.5f*yc1.w - 0.5f*ay[7]);
    *(float4*)(Zo)     = make_float4(1.5f*zc0.x - 0.5f*az[0], 1.5f*zc0.y - 0.5f*az[1],
                                     1.5f*zc0.z - 0.5f*az[2], 1.5f*zc0.w - 0.5f*az[3]);
    *(float4*)(Zo + 4) = make_float4(1.5f*zc1.x - 0.5f*az[4], 1.5f*zc1.y - 0.5f*az[5],
                                     1.5f*zc1.z - 0.5f*az[6], 1.5f*zc1.w - 0.5f*az[7]);
}

// ============ K5: WT = (Z*rsqrt(c))^T bf16 ; muW = mu . W =====================
__global__ __launch_bounds__(256) void k_wprep(
    const float* __restrict__ Z, const float* __restrict__ scale,
    const float* __restrict__ mean,
    unsigned short* __restrict__ WT, float* __restrict__ muW)
{
    __shared__ float Zs[128][129];
    __shared__ float mu[128];
    const int g = blockIdx.x;
    const int t = threadIdx.x;
    const float sc = scale[g];
    if (t < 128) mu[t] = mean[g * GD + t];
    for (int k = 0; k < 64; ++k) {
        int e = t + 256 * k;
        Zs[e >> 7][e & 127] = Z[(size_t)g * (GD * GD) + e];
    }
    __syncthreads();
    const int n = t & 127, kh = t >> 7;
    unsigned short* o = WT + (size_t)g * (GD * GD) + (size_t)n * GD + kh * 64;
    for (int k = 0; k < 64; k += 2) {
        unsigned int pk = (unsigned int)f2bf(Zs[kh * 64 + k][n] * sc)
                        | ((unsigned int)f2bf(Zs[kh * 64 + k + 1][n] * sc) << 16);
        *(unsigned int*)(o + k) = pk;
    }
    if (t < 128) {
        float s = 0.f;
        for (int d = 0; d < 128; ++d) s = fmaf(mu[d], Zs[d][t], s);
        muW[g * GD + t] = s * sc;
    }
}

// ============ K6: out = x * W - muW  (A-frags from fp32 x, no LDS) ============
// grid 8192 = 32 groups x 256 row-blocks (64 rows each); 256 thr (4 waves).
__global__ __launch_bounds__(256) void k_apply(
    const float* __restrict__ x, const unsigned short* __restrict__ WT,
    const float* __restrict__ muW, float* __restrict__ out)
{
    const int bid = blockIdx.x;
    const int g = bid >> 8, rb = bid & 255;
    const int t = threadIdx.x;
    const int lane = t & 63, w = t >> 6;
    const int lm = lane & 15, lk = lane >> 4;
    const int nh = w >> 1;              // n-half (64 cols)
    const int m0w = (w & 1) * 32;       // row offset within 64-row block
    const int row0 = rb * 64;

    bf16x8 Wf[4][4];
    {
        const unsigned short* wg = WT + (size_t)g * (GD * GD);
#pragma unroll
        for (int ni = 0; ni < 4; ++ni)
#pragma unroll
            for (int ks = 0; ks < 4; ++ks)
                Wf[ni][ks] = *(const bf16x8*)(wg
                    + (size_t)(nh * 64 + ni * 16 + lm) * GD + ks * 32 + lk * 8);
    }
    const float* ab = x + (size_t)(row0 + m0w) * NCOLS + g * GD;

    f32x4 acc[2][4];
#pragma unroll
    for (int mi = 0; mi < 2; ++mi)
#pragma unroll
        for (int ni = 0; ni < 4; ++ni) acc[mi][ni] = (f32x4){0.f, 0.f, 0.f, 0.f};

#pragma unroll
    for (int ks = 0; ks < 4; ++ks) {
        const float* pa0 = ab + (size_t)lm * NCOLS + ks * 32 + lk * 8;
        const float* pa1 = pa0 + (size_t)16 * NCOLS;
        float4 u0 = *(const float4*)(pa0);
        float4 u1 = *(const float4*)(pa0 + 4);
        float4 u2 = *(const float4*)(pa1);
        float4 u3 = *(const float4*)(pa1 + 4);
        bf16x8 a0, a1;
        a0[0] = (short)f2bf(u0.x); a0[1] = (short)f2bf(u0.y);
        a0[2] = (short)f2bf(u0.z); a0[3] = (short)f2bf(u0.w);
        a0[4] = (short)f2bf(u1.x); a0[5] = (short)f2bf(u1.y);
        a0[6] = (short)f2bf(u1.z); a0[7] = (short)f2bf(u1.w);
        a1[0] = (short)f2bf(u2.x); a1[1] = (short)f2bf(u2.y);
        a1[2] = (short)f2bf(u2.z); a1[3] = (short)f2bf(u2.w);
        a1[4] = (short)f2bf(u3.x); a1[5] = (short)f2bf(u3.y);
        a1[6] = (short)f2bf(u3.z); a1[7] = (short)f2bf(u3.w);
#pragma unroll
        for (int ni = 0; ni < 4; ++ni) {
            acc[0][ni] = __builtin_amdgcn_mfma_f32_16x16x32_bf16(
                a0, Wf[ni][ks], acc[0][ni], 0, 0, 0);
            acc[1][ni] = __builtin_amdgcn_mfma_f32_16x16x32_bf16(
                a1, Wf[ni][ks], acc[1][ni], 0, 0, 0);
        }
    }
    const float* mg = muW + g * GD;
    float mw[4];
#pragma unroll
    for (int ni = 0; ni < 4; ++ni) mw[ni] = mg[nh * 64 + ni * 16 + lm];

    float* ob = out + (size_t)(row0 + m0w) * NCOLS + g * GD + nh * 64;
#pragma unroll
    for (int mi = 0; mi < 2; ++mi)
#pragma unroll
        for (int ni = 0; ni < 4; ++ni)
#pragma unroll
            for (int r = 0; r < 4; ++r)
                ob[(size_t)(mi * 16 + lk * 4 + r) * NCOLS + ni * 16 + lm]
                    = acc[mi][ni][r] - mw[ni];
}

extern "C" void kernel_launch(void* const* d_in, const int* in_sizes, int n_in,
                              void* d_out, int out_size, void* d_ws, size_t ws_size,
                              hipStream_t stream) {
    const float* x = (const float*)d_in[0];
    float* out = (float*)d_out;
    float* ws = (float*)d_ws;

    float* xtx   = ws;                                    // 8,388,608 f
    float* ps    = xtx + (size_t)NG * NPC * GD * GD;      // 2,097,152 f
    float* mean  = ps + (size_t)NPB * NCOLS;              // 4,096
    float* scale = mean + NCOLS;                          // 32
    float* Cbuf  = scale + 32;                            // 524,288
    float* Ya    = Cbuf + (size_t)NG * GD * GD;
    float* Za    = Ya + (size_t)NG * GD * GD;
    float* Yb    = Za + (size_t)NG * GD * GD;
    float* Zb    = Yb + (size_t)NG * GD * GD;
    float* muW   = Zb + (size_t)NG * GD * GD;             // 4,096
    unsigned short* WT = (unsigned short*)(muW + NCOLS);  // 2,097,152 sh (4 MB)
    unsigned short* xT = WT + (size_t)NG * GD * GD;       // 67,108,864 sh (128 MB)

    k_pack<<<NPB, 256, 0, stream>>>(x, xT, ps);
    k_mean<<<NCOLS / 256, 256, 0, stream>>>(ps, mean);
    k_cov<<<NG * NPC, 256, 0, stream>>>(xT, xtx);
    k_covreduce<<<NG * NPC, 256, 0, stream>>>(xtx, mean, Cbuf);
    k_prep<<<NG, 256, 0, stream>>>(Cbuf, scale, Ya, Za);
    for (int it = 0; it < 6; ++it) {
        if ((it & 1) == 0)
            k_ns_iter<<<NG * 8, 256, 0, stream>>>(Ya, Za, Yb, Zb);
        else
            k_ns_iter<<<NG * 8, 256, 0, stream>>>(Yb, Zb, Ya, Za);
    }
    k_wprep<<<NG, 256, 0, stream>>>(Za, scale, mean, WT, muW);
    k_apply<<<NG * 256, 256, 0, stream>>>(x, WT, muW, out);
}

// Round 5
// 588.162 us; speedup vs baseline: 1.9019x; 1.2094x over previous
//
#include <hip/hip_runtime.h>
#include <cstddef>

#define NROWS 16384
#define NCOLS 4096
#define NG 32
#define GD 128
#define NPC 16              // K-stripes (1024 samples each)
#define NPB 512             // pack blocks (32 samples each)

typedef float f32x4 __attribute__((ext_vector_type(4)));
typedef short bf16x8 __attribute__((ext_vector_type(8)));

__device__ inline unsigned short f2bf(float f) {
    unsigned int u = __builtin_bit_cast(unsigned int, f);
    u += 0x7fffu + ((u >> 16) & 1u);
    return (unsigned short)(u >> 16);
}

// ============ K0: pack x -> transposed bf16 xT[g*16+p][d][1024] + col partials =
// grid 512 x 256 thr; block = 32 consecutive samples.
__global__ __launch_bounds__(256) void k_pack(
    const float* __restrict__ x, unsigned short* __restrict__ xT,
    float* __restrict__ ps)
{
    __shared__ unsigned short tT[128][40];   // [feat][sample] bf16, 80 B rows
    const int b = blockIdx.x;
    const int p = b >> 5;            // K-stripe
    const int r0l = (b & 31) * 32;   // sample offset within stripe
    const int r0 = b * 32;           // global sample
    const int t = threadIdx.x;
    const int r = t >> 3;            // 0..31
    const int c0 = (t & 7) * 4;
    const int d = t >> 1, hf = t & 1;

    for (int g = 0; g < NG; ++g) {
        __syncthreads();
#pragma unroll
        for (int j = 0; j < 4; ++j) {
            const int c = c0 + 32 * j;
            float4 v = *(const float4*)(x + (size_t)(r0 + r) * NCOLS + g * GD + c);
            tT[c + 0][r] = f2bf(v.x);
            tT[c + 1][r] = f2bf(v.y);
            tT[c + 2][r] = f2bf(v.z);
            tT[c + 3][r] = f2bf(v.w);
        }
        __syncthreads();
        // transposed write: thread -> feature d, 16 samples (hf half)
        uint4 q0 = *(const uint4*)&tT[d][hf * 16];
        uint4 q1 = *(const uint4*)&tT[d][hf * 16 + 8];
        unsigned short* o = xT + ((size_t)(g * NPC + p) * GD + d) * 1024 + r0l + hf * 16;
        *(uint4*)(o) = q0;
        *(uint4*)(o + 8) = q1;
        // column partial sums (32 samples) from the bf16 values
        float s = 0.f;
        {
            unsigned int ws[8] = {q0.x, q0.y, q0.z, q0.w, q1.x, q1.y, q1.z, q1.w};
#pragma unroll
            for (int i = 0; i < 8; ++i) {
                s += __builtin_bit_cast(float, ws[i] << 16);
                s += __builtin_bit_cast(float, ws[i] & 0xffff0000u);
            }
        }
        s += __shfl_xor(s, 1);
        if (hf == 0) ps[(size_t)b * NCOLS + g * GD + d] = s;
    }
}

// ============ K0b: reduce partial colsums -> mean ==============================
__global__ __launch_bounds__(256) void k_mean(
    const float* __restrict__ ps, float* __restrict__ mean)
{
    const int col = blockIdx.x * 256 + threadIdx.x;
    float s0 = 0.f, s1 = 0.f, s2 = 0.f, s3 = 0.f;
    for (int b = 0; b < NPB; b += 4) {
        s0 += ps[(size_t)(b + 0) * NCOLS + col];
        s1 += ps[(size_t)(b + 1) * NCOLS + col];
        s2 += ps[(size_t)(b + 2) * NCOLS + col];
        s3 += ps[(size_t)(b + 3) * NCOLS + col];
    }
    mean[col] = (s0 + s1 + s2 + s3) * (1.0f / (float)NROWS);
}

// ============ K1: register-only MFMA partial X^T X from xT ====================
// grid 512 = 32 g x 16 stripes; 256 thr (4 waves); no LDS.
// ALL fragment register indices are compile-time static (rule #20 fix).
__global__ __launch_bounds__(256) void k_cov(
    const unsigned short* __restrict__ xT, float* __restrict__ xtx)
{
    const int bid = blockIdx.x;
    const int t = threadIdx.x;
    const int w = t >> 6, lane = t & 63;
    const int lm = lane & 15, lk = lane >> 4;
    const unsigned short* gb = xT + (size_t)bid * (GD * 1024) + lk * 8;
    // this wave's A rows (named, no dynamic indexing):
    const unsigned short* pa = gb + (size_t)(w * 32 + lm) * 1024;
    // B row base (rows lm + 16n, n const-unrolled):
    const unsigned short* pb = gb + (size_t)lm * 1024;

    f32x4 acc[2][8];
#pragma unroll
    for (int mi = 0; mi < 2; ++mi)
#pragma unroll
        for (int ni = 0; ni < 8; ++ni) acc[mi][ni] = (f32x4){0.f, 0.f, 0.f, 0.f};

    bf16x8 A0, A1, B[8], A0n, A1n, Bn[8];

#define CLD(AX0, AX1, BX, KS) { \
    AX0 = *(const bf16x8*)(pa + (KS) * 32); \
    AX1 = *(const bf16x8*)(pa + 16384 + (KS) * 32); \
    _Pragma("unroll") for (int n = 0; n < 8; ++n) \
        BX[n] = *(const bf16x8*)(pb + n * 16384 + (KS) * 32); }

#define CFMA(AX0, AX1, BX) { \
    _Pragma("unroll") for (int n = 0; n < 8; ++n) { \
        acc[0][n] = __builtin_amdgcn_mfma_f32_16x16x32_bf16(AX0, BX[n], acc[0][n], 0, 0, 0); \
        acc[1][n] = __builtin_amdgcn_mfma_f32_16x16x32_bf16(AX1, BX[n], acc[1][n], 0, 0, 0); } }

    CLD(A0, A1, B, 0);
    for (int ks = 0; ks < 32; ks += 2) {
        CLD(A0n, A1n, Bn, ks + 1);
        CFMA(A0, A1, B);
        if (ks + 2 < 32) { CLD(A0, A1, B, ks + 2); }
        CFMA(A0n, A1n, Bn);
    }
#undef CLD
#undef CFMA

    float* ob = xtx + (size_t)bid * (GD * GD);
#pragma unroll
    for (int mi = 0; mi < 2; ++mi)
#pragma unroll
        for (int ni = 0; ni < 8; ++ni) {
            const int i0 = w * 32 + mi * 16 + lk * 4;
            const int j = ni * 16 + lm;
#pragma unroll
            for (int r = 0; r < 4; ++r)
                ob[(size_t)(i0 + r) * GD + j] = acc[mi][ni][r];
        }
}

// ============ K2: reduce partials -> C (mean-corrected) =======================
__global__ __launch_bounds__(256) void k_covreduce(
    const float* __restrict__ xtx, const float* __restrict__ mean,
    float* __restrict__ C)
{
    __shared__ float mu[128];
    const int bid = blockIdx.x;
    const int g = bid >> 4, s = bid & 15;
    const int t = threadIdx.x;
    if (t < 128) mu[t] = mean[g * GD + t];
    __syncthreads();
    const int e = s * 1024 + t * 4;
    const int i = e >> 7, j = e & 127;
    float4 sum = make_float4(0.f, 0.f, 0.f, 0.f);
#pragma unroll
    for (int p = 0; p < NPC; ++p) {
        const float4 vv = *(const float4*)(xtx + ((size_t)(g * NPC + p) << 14) + e);
        sum.x += vv.x; sum.y += vv.y; sum.z += vv.z; sum.w += vv.w;
    }
    const float inv = 1.0f / (float)(NROWS - 1);
    const float mi2 = (float)NROWS * mu[i];
    float4 r;
    r.x = (sum.x - mi2 * mu[j + 0]) * inv;
    r.y = (sum.y - mi2 * mu[j + 1]) * inv;
    r.z = (sum.z - mi2 * mu[j + 2]) * inv;
    r.w = (sum.w - mi2 * mu[j + 3]) * inv;
    *(float4*)(C + (size_t)g * (GD * GD) + e) = r;
}

// ============ K3: Gershgorin scale + Y0/Z0 ====================================
__global__ __launch_bounds__(256) void k_prep(
    const float* __restrict__ Cg, float* __restrict__ scale,
    float* __restrict__ Y0, float* __restrict__ Z0)
{
    __shared__ float Cs[128][129];
    __shared__ float rs[128];
    __shared__ float sinv[1];
    const int g = blockIdx.x;
    const int t = threadIdx.x;
    for (int k = 0; k < 64; ++k) {
        int e = t + 256 * k;
        Cs[e >> 7][e & 127] = Cg[(size_t)g * (GD * GD) + e];
    }
    __syncthreads();
    if (t < 128) {
        float s = 0.f;
        for (int i = 0; i < 128; ++i) s += fabsf(Cs[i][t]);
        rs[t] = s;
    }
    __syncthreads();
    if (t == 0) {
        float up = 0.f, lo = 1e30f;
        for (int i = 0; i < 128; ++i) {
            up = fmaxf(up, rs[i]);
            lo = fminf(lo, 2.0f * Cs[i][i] - rs[i]);
        }
        float c = 0.5f * (up + fmaxf(lo, 0.0f));
        c = fmaxf(c, 1e-20f);
        sinv[0] = 1.0f / c;
        scale[g] = rsqrtf(c);
    }
    __syncthreads();
    const float invc = sinv[0];
    for (int k = 0; k < 64; ++k) {
        int e = t + 256 * k;
        int i = e >> 7, j = e & 127;
        Y0[(size_t)g * (GD * GD) + e] = Cs[i][j] * invc;
        Z0[(size_t)g * (GD * GD) + e] = (i == j) ? 1.0f : 0.0f;
    }
}

// ============ K4: Newton-Schulz iteration (fp32) ==============================
__global__ __launch_bounds__(256) void k_ns_iter(
    const float* __restrict__ Yin, const float* __restrict__ Zin,
    float* __restrict__ Yout, float* __restrict__ Zout)
{
    __shared__ float Ys[128][132];
    __shared__ float Zs[128][132];
    __shared__ float Ts[128][16];
    const int bid = blockIdx.x;
    const int g = bid >> 3;
    const int sl = bid & 7;
    const int J0 = sl * 16;
    const int t = threadIdx.x;
    const float* Yg = Yin + (size_t)g * GD * GD;
    const float* Zg = Zin + (size_t)g * GD * GD;
#pragma unroll
    for (int k = 0; k < 16; ++k) {
        int q = t + 256 * k;
        int row = q >> 5, c4 = q & 31;
        *(float4*)&Ys[row][c4 * 4] = *(const float4*)(Yg + (size_t)q * 4);
        *(float4*)&Zs[row][c4 * 4] = *(const float4*)(Zg + (size_t)q * 4);
    }
    __syncthreads();
    const int i = t >> 1;
    const int jb = (t & 1) * 8;

    float accT[8];
#pragma unroll
    for (int q = 0; q < 8; ++q) accT[q] = 0.f;
    for (int k4 = 0; k4 < 32; ++k4) {
        float4 zv = *(const float4*)&Zs[i][k4 * 4];
        float zz[4] = {zv.x, zv.y, zv.z, zv.w};
#pragma unroll
        for (int e = 0; e < 4; ++e) {
            const int k = k4 * 4 + e;
            float4 y0 = *(const float4*)&Ys[k][J0 + jb];
            float4 y1 = *(const float4*)&Ys[k][J0 + jb + 4];
            float yy[8] = {y0.x, y0.y, y0.z, y0.w, y1.x, y1.y, y1.z, y1.w};
#pragma unroll
            for (int q = 0; q < 8; ++q) accT[q] = fmaf(zz[e], yy[q], accT[q]);
        }
    }
#pragma unroll
    for (int q = 0; q < 8; ++q) Ts[i][jb + q] = accT[q];
    __syncthreads();

    float ay[8], az[8];
#pragma unroll
    for (int q = 0; q < 8; ++q) { ay[q] = 0.f; az[q] = 0.f; }
    for (int k4 = 0; k4 < 32; ++k4) {
        float4 yv = *(const float4*)&Ys[i][k4 * 4];
        float4 zv = *(const float4*)&Zs[i][k4 * 4];
        float yy[4] = {yv.x, yv.y, yv.z, yv.w};
        float zz[4] = {zv.x, zv.y, zv.z, zv.w};
#pragma unroll
        for (int e = 0; e < 4; ++e) {
            const int k = k4 * 4 + e;
            float4 t0 = *(const float4*)&Ts[k][jb];
            float4 t1 = *(const float4*)&Ts[k][jb + 4];
            float tt[8] = {t0.x, t0.y, t0.z, t0.w, t1.x, t1.y, t1.z, t1.w};
#pragma unroll
            for (int q = 0; q < 8; ++q) {
                ay[q] = fmaf(yy[e], tt[q], ay[q]);
                az[q] = fmaf(zz[e], tt[q], az[q]);
            }
        }
    }
    float4 yc0 = *(const float4*)&Ys[i][J0 + jb];
    float4 yc1 = *(const float4*)&Ys[i][J0 + jb + 4];
    float4 zc0 = *(const float4*)&Zs[i][J0 + jb];
    float4 zc1 = *(const float4*)&Zs[i][J0 + jb + 4];
    float* Yo = Yout + (size_t)g * GD * GD + (size_t)i * GD + J0 + jb;
    float* Zo = Zout + (size_t)g * GD * GD + (size_t)i * GD + J0 + jb;
    *(float4*)(Yo)     = make_float4(1.5f*yc0.x - 0.5f*ay[0], 1.5f*yc0.y - 0.5f*ay[1],
                                     1.5f*yc0.z - 0.5f*ay[2], 1.5f*yc0.w - 0.5f*ay[3]);
    *(float4*)(Yo + 4) = make_float4(1.5f*yc1.x - 0.5f*ay[4], 1.5f*yc1.y - 0.5f*ay[5],
                                     1.5f*yc1.z - 0.5f*ay[6], 1.5f*yc1.w - 0.5f*ay[7]);
    *(float4*)(Zo)     = make_float4(1.5f*zc0.x - 0.5f*az[0], 1.5f*zc0.y - 0.5f*az[1],
                                     1.5f*zc0.z - 0.5f*az[2], 1.5f*zc0.w - 0.5f*az[3]);
    *(float4*)(Zo + 4) = make_float4(1.5f*zc1.x - 0.5f*az[4], 1.5f*zc1.y - 0.5f*az[5],
                                     1.5f*zc1.z - 0.5f*az[6], 1.5f*zc1.w - 0.5f*az[7]);
}

// ============ K5: WT = (Z*rsqrt(c))^T bf16 ; muW = mu . W =====================
__global__ __launch_bounds__(256) void k_wprep(
    const float* __restrict__ Z, const float* __restrict__ scale,
    const float* __restrict__ mean,
    unsigned short* __restrict__ WT, float* __restrict__ muW)
{
    __shared__ float Zs[128][129];
    __shared__ float mu[128];
    const int g = blockIdx.x;
    const int t = threadIdx.x;
    const float sc = scale[g];
    if (t < 128) mu[t] = mean[g * GD + t];
    for (int k = 0; k < 64; ++k) {
        int e = t + 256 * k;
        Zs[e >> 7][e & 127] = Z[(size_t)g * (GD * GD) + e];
    }
    __syncthreads();
    const int n = t & 127, kh = t >> 7;
    unsigned short* o = WT + (size_t)g * (GD * GD) + (size_t)n * GD + kh * 64;
    for (int k = 0; k < 64; k += 2) {
        unsigned int pk = (unsigned int)f2bf(Zs[kh * 64 + k][n] * sc)
                        | ((unsigned int)f2bf(Zs[kh * 64 + k + 1][n] * sc) << 16);
        *(unsigned int*)(o + k) = pk;
    }
    if (t < 128) {
        float s = 0.f;
        for (int d = 0; d < 128; ++d) s = fmaf(mu[d], Zs[d][t], s);
        muW[g * GD + t] = s * sc;
    }
}

// ============ K6: out = x * W - muW  (A-frags from fp32 x, no LDS) ============
// grid 8192 = 32 groups x 256 row-blocks (64 rows each); 256 thr (4 waves).
__global__ __launch_bounds__(256) void k_apply(
    const float* __restrict__ x, const unsigned short* __restrict__ WT,
    const float* __restrict__ muW, float* __restrict__ out)
{
    const int bid = blockIdx.x;
    const int g = bid >> 8, rb = bid & 255;
    const int t = threadIdx.x;
    const int lane = t & 63, w = t >> 6;
    const int lm = lane & 15, lk = lane >> 4;
    const int nh = w >> 1;              // n-half (64 cols)
    const int m0w = (w & 1) * 32;       // row offset within 64-row block
    const int row0 = rb * 64;

    bf16x8 Wf[4][4];
    {
        const unsigned short* wg = WT + (size_t)g * (GD * GD);
#pragma unroll
        for (int ni = 0; ni < 4; ++ni)
#pragma unroll
            for (int ks = 0; ks < 4; ++ks)
                Wf[ni][ks] = *(const bf16x8*)(wg
                    + (size_t)(nh * 64 + ni * 16 + lm) * GD + ks * 32 + lk * 8);
    }
    const float* ab = x + (size_t)(row0 + m0w) * NCOLS + g * GD;

    f32x4 acc[2][4];
#pragma unroll
    for (int mi = 0; mi < 2; ++mi)
#pragma unroll
        for (int ni = 0; ni < 4; ++ni) acc[mi][ni] = (f32x4){0.f, 0.f, 0.f, 0.f};

#pragma unroll
    for (int ks = 0; ks < 4; ++ks) {
        const float* pa0 = ab + (size_t)lm * NCOLS + ks * 32 + lk * 8;
        const float* pa1 = pa0 + (size_t)16 * NCOLS;
        float4 u0 = *(const float4*)(pa0);
        float4 u1 = *(const float4*)(pa0 + 4);
        float4 u2 = *(const float4*)(pa1);
        float4 u3 = *(const float4*)(pa1 + 4);
        bf16x8 a0, a1;
        a0[0] = (short)f2bf(u0.x); a0[1] = (short)f2bf(u0.y);
        a0[2] = (short)f2bf(u0.z); a0[3] = (short)f2bf(u0.w);
        a0[4] = (short)f2bf(u1.x); a0[5] = (short)f2bf(u1.y);
        a0[6] = (short)f2bf(u1.z); a0[7] = (short)f2bf(u1.w);
        a1[0] = (short)f2bf(u2.x); a1[1] = (short)f2bf(u2.y);
        a1[2] = (short)f2bf(u2.z); a1[3] = (short)f2bf(u2.w);
        a1[4] = (short)f2bf(u3.x); a1[5] = (short)f2bf(u3.y);
        a1[6] = (short)f2bf(u3.z); a1[7] = (short)f2bf(u3.w);
#pragma unroll
        for (int ni = 0; ni < 4; ++ni) {
            acc[0][ni] = __builtin_amdgcn_mfma_f32_16x16x32_bf16(
                a0, Wf[ni][ks], acc[0][ni], 0, 0, 0);
            acc[1][ni] = __builtin_amdgcn_mfma_f32_16x16x32_bf16(
                a1, Wf[ni][ks], acc[1][ni], 0, 0, 0);
        }
    }
    const float* mg = muW + g * GD;
    float mw[4];
#pragma unroll
    for (int ni = 0; ni < 4; ++ni) mw[ni] = mg[nh * 64 + ni * 16 + lm];

    float* ob = out + (size_t)(row0 + m0w) * NCOLS + g * GD + nh * 64;
#pragma unroll
    for (int mi = 0; mi < 2; ++mi)
#pragma unroll
        for (int ni = 0; ni < 4; ++ni)
#pragma unroll
            for (int r = 0; r < 4; ++r)
                ob[(size_t)(mi * 16 + lk * 4 + r) * NCOLS + ni * 16 + lm]
                    = acc[mi][ni][r] - mw[ni];
}

extern "C" void kernel_launch(void* const* d_in, const int* in_sizes, int n_in,
                              void* d_out, int out_size, void* d_ws, size_t ws_size,
                              hipStream_t stream) {
    const float* x = (const float*)d_in[0];
    float* out = (float*)d_out;
    float* ws = (float*)d_ws;

    float* xtx   = ws;                                    // 8,388,608 f
    float* ps    = xtx + (size_t)NG * NPC * GD * GD;      // 2,097,152 f
    float* mean  = ps + (size_t)NPB * NCOLS;              // 4,096
    float* scale = mean + NCOLS;                          // 32
    float* Cbuf  = scale + 32;                            // 524,288
    float* Ya    = Cbuf + (size_t)NG * GD * GD;
    float* Za    = Ya + (size_t)NG * GD * GD;
    float* Yb    = Za + (size_t)NG * GD * GD;
    float* Zb    = Yb + (size_t)NG * GD * GD;
    float* muW   = Zb + (size_t)NG * GD * GD;             // 4,096
    unsigned short* WT = (unsigned short*)(muW + NCOLS);  // 2,097,152 sh (4 MB)
    unsigned short* xT = WT + (size_t)NG * GD * GD;       // 67,108,864 sh (128 MB)

    k_pack<<<NPB, 256, 0, stream>>>(x, xT, ps);
    k_mean<<<NCOLS / 256, 256, 0, stream>>>(ps, mean);
    k_cov<<<NG * NPC, 256, 0, stream>>>(xT, xtx);
    k_covreduce<<<NG * NPC, 256, 0, stream>>>(xtx, mean, Cbuf);
    k_prep<<<NG, 256, 0, stream>>>(Cbuf, scale, Ya, Za);
    for (int it = 0; it < 6; ++it) {
        if ((it & 1) == 0)
            k_ns_iter<<<NG * 8, 256, 0, stream>>>(Ya, Za, Yb, Zb);
        else
            k_ns_iter<<<NG * 8, 256, 0, stream>>>(Yb, Zb, Ya, Za);
    }
    k_wprep<<<NG, 256, 0, stream>>>(Za, scale, mean, WT, muW);
    k_apply<<<NG * 256, 256, 0, stream>>>(x, WT, muW, out);
}

// Round 6
// 447.067 us; speedup vs baseline: 2.5022x; 1.3156x over previous
//
#include <hip/hip_runtime.h>
#include <cstddef>

#define NROWS 16384
#define NCOLS 4096
#define NG 32
#define GD 128
#define NPC 16              // K-stripes (1024 samples each)

typedef float f32x4 __attribute__((ext_vector_type(4)));
typedef short bf16x8 __attribute__((ext_vector_type(8)));

__device__ inline unsigned short f2bf(float f) {
    unsigned int u = __builtin_bit_cast(unsigned int, f);
    u += 0x7fffu + ((u >> 16) & 1u);
    return (unsigned short)(u >> 16);
}

// ============ K0: pack x -> transposed bf16 xT[g*16+p][d][1024] + col partials =
// grid 1024 = (g, p, half); 256 thr; 8 iters x 64 samples; fp32 LDS transpose.
__global__ __launch_bounds__(256) void k_pack(
    const float* __restrict__ x, unsigned short* __restrict__ xT,
    float* __restrict__ ps)
{
    __shared__ float T[64][133];     // padded: bank = (5s + c) % 32
    __shared__ float csum2[128];
    const int b = blockIdx.x;
    const int g = b >> 5;
    const int p = (b >> 1) & 15;
    const int hh = b & 1;
    const int t = threadIdx.x;
    const int s = t >> 2;            // staging row 0..63
    const int kq = t & 3;
    const int d = t & 127, sh = t >> 7;
    const int base = p * 1024 + hh * 512;

    float psum = 0.f;
    unsigned short* orow = xT + ((size_t)(g * NPC + p) * GD + d) * 1024
                              + hh * 512 + sh * 32;

    for (int it = 0; it < 8; ++it) {
        if (it) __syncthreads();
        const int srow = base + it * 64;
        const float* xr = x + (size_t)(srow + s) * NCOLS + g * GD + kq * 4;
#pragma unroll
        for (int i = 0; i < 8; ++i) {
            float4 v = *(const float4*)(xr + 16 * i);
            *(float4*)&T[s][kq * 4 + 16 * i] = v;
        }
        __syncthreads();
        unsigned int pk[16];
#pragma unroll
        for (int j = 0; j < 16; ++j) {
            float f0 = T[sh * 32 + 2 * j][d];
            float f1 = T[sh * 32 + 2 * j + 1][d];
            psum += f0 + f1;
            pk[j] = (unsigned int)f2bf(f0) | ((unsigned int)f2bf(f1) << 16);
        }
        unsigned short* o = orow + it * 64;
        *(uint4*)(o)      = make_uint4(pk[0], pk[1], pk[2], pk[3]);
        *(uint4*)(o + 8)  = make_uint4(pk[4], pk[5], pk[6], pk[7]);
        *(uint4*)(o + 16) = make_uint4(pk[8], pk[9], pk[10], pk[11]);
        *(uint4*)(o + 24) = make_uint4(pk[12], pk[13], pk[14], pk[15]);
    }
    if (sh == 1) csum2[d] = psum;
    __syncthreads();
    if (sh == 0)
        ps[(size_t)((g * NPC + p) * 2 + hh) * GD + d] = psum + csum2[d];
}

// ============ K0b: reduce partial colsums -> mean ==============================
__global__ __launch_bounds__(256) void k_mean(
    const float* __restrict__ ps, float* __restrict__ mean)
{
    const int col = blockIdx.x * 256 + threadIdx.x;
    const int g = col >> 7, d = col & 127;
    float s = 0.f;
#pragma unroll
    for (int q = 0; q < 32; ++q) s += ps[(size_t)(g * 32 + q) * GD + d];
    mean[col] = s * (1.0f / (float)NROWS);
}

// ============ K1: register-only MFMA partial X^T X from xT ====================
// grid 512 = 32 g x 16 stripes; 256 thr (4 waves); no LDS; static frag indices.
__global__ __launch_bounds__(256) void k_cov(
    const unsigned short* __restrict__ xT, float* __restrict__ xtx)
{
    const int bid = blockIdx.x;
    const int t = threadIdx.x;
    const int w = t >> 6, lane = t & 63;
    const int lm = lane & 15, lk = lane >> 4;
    const unsigned short* gb = xT + (size_t)bid * (GD * 1024) + lk * 8;
    const unsigned short* pa = gb + (size_t)(w * 32 + lm) * 1024;
    const unsigned short* pb = gb + (size_t)lm * 1024;

    f32x4 acc[2][8];
#pragma unroll
    for (int mi = 0; mi < 2; ++mi)
#pragma unroll
        for (int ni = 0; ni < 8; ++ni) acc[mi][ni] = (f32x4){0.f, 0.f, 0.f, 0.f};

    bf16x8 A0, A1, B[8], A0n, A1n, Bn[8];

#define CLD(AX0, AX1, BX, KS) { \
    AX0 = *(const bf16x8*)(pa + (KS) * 32); \
    AX1 = *(const bf16x8*)(pa + 16384 + (KS) * 32); \
    _Pragma("unroll") for (int n = 0; n < 8; ++n) \
        BX[n] = *(const bf16x8*)(pb + n * 16384 + (KS) * 32); }

#define CFMA(AX0, AX1, BX) { \
    _Pragma("unroll") for (int n = 0; n < 8; ++n) { \
        acc[0][n] = __builtin_amdgcn_mfma_f32_16x16x32_bf16(AX0, BX[n], acc[0][n], 0, 0, 0); \
        acc[1][n] = __builtin_amdgcn_mfma_f32_16x16x32_bf16(AX1, BX[n], acc[1][n], 0, 0, 0); } }

    CLD(A0, A1, B, 0);
    for (int ks = 0; ks < 32; ks += 2) {
        CLD(A0n, A1n, Bn, ks + 1);
        CFMA(A0, A1, B);
        if (ks + 2 < 32) { CLD(A0, A1, B, ks + 2); }
        CFMA(A0n, A1n, Bn);
    }
#undef CLD
#undef CFMA

    float* ob = xtx + (size_t)bid * (GD * GD);
#pragma unroll
    for (int mi = 0; mi < 2; ++mi)
#pragma unroll
        for (int ni = 0; ni < 8; ++ni) {
            const int i0 = w * 32 + mi * 16 + lk * 4;
            const int j = ni * 16 + lm;
#pragma unroll
            for (int r = 0; r < 4; ++r)
                ob[(size_t)(i0 + r) * GD + j] = acc[mi][ni][r];
        }
}

// ============ K2: reduce partials -> C (mean-corrected) =======================
__global__ __launch_bounds__(256) void k_covreduce(
    const float* __restrict__ xtx, const float* __restrict__ mean,
    float* __restrict__ C)
{
    __shared__ float mu[128];
    const int bid = blockIdx.x;
    const int g = bid >> 4, s = bid & 15;
    const int t = threadIdx.x;
    if (t < 128) mu[t] = mean[g * GD + t];
    __syncthreads();
    const int e = s * 1024 + t * 4;
    const int i = e >> 7, j = e & 127;
    float4 sum = make_float4(0.f, 0.f, 0.f, 0.f);
#pragma unroll
    for (int p = 0; p < NPC; ++p) {
        const float4 vv = *(const float4*)(xtx + ((size_t)(g * NPC + p) << 14) + e);
        sum.x += vv.x; sum.y += vv.y; sum.z += vv.z; sum.w += vv.w;
    }
    const float inv = 1.0f / (float)(NROWS - 1);
    const float mi2 = (float)NROWS * mu[i];
    float4 r;
    r.x = (sum.x - mi2 * mu[j + 0]) * inv;
    r.y = (sum.y - mi2 * mu[j + 1]) * inv;
    r.z = (sum.z - mi2 * mu[j + 2]) * inv;
    r.w = (sum.w - mi2 * mu[j + 3]) * inv;
    *(float4*)(C + (size_t)g * (GD * GD) + e) = r;
}

// ============ K3: Gershgorin scale + Y0/Z0 ====================================
__global__ __launch_bounds__(256) void k_prep(
    const float* __restrict__ Cg, float* __restrict__ scale,
    float* __restrict__ Y0, float* __restrict__ Z0)
{
    __shared__ float Cs[128][129];
    __shared__ float rs[128];
    __shared__ float sinv[1];
    const int g = blockIdx.x;
    const int t = threadIdx.x;
    for (int k = 0; k < 64; ++k) {
        int e = t + 256 * k;
        Cs[e >> 7][e & 127] = Cg[(size_t)g * (GD * GD) + e];
    }
    __syncthreads();
    if (t < 128) {
        float s = 0.f;
        for (int i = 0; i < 128; ++i) s += fabsf(Cs[i][t]);
        rs[t] = s;
    }
    __syncthreads();
    if (t == 0) {
        float up = 0.f, lo = 1e30f;
        for (int i = 0; i < 128; ++i) {
            up = fmaxf(up, rs[i]);
            lo = fminf(lo, 2.0f * Cs[i][i] - rs[i]);
        }
        float c = 0.5f * (up + fmaxf(lo, 0.0f));
        c = fmaxf(c, 1e-20f);
        sinv[0] = 1.0f / c;
        scale[g] = rsqrtf(c);
    }
    __syncthreads();
    const float invc = sinv[0];
    for (int k = 0; k < 64; ++k) {
        int e = t + 256 * k;
        int i = e >> 7, j = e & 127;
        Y0[(size_t)g * (GD * GD) + e] = Cs[i][j] * invc;
        Z0[(size_t)g * (GD * GD) + e] = (i == j) ? 1.0f : 0.0f;
    }
}

// ============ K4: Newton-Schulz iteration (fp32) ==============================
__global__ __launch_bounds__(256) void k_ns_iter(
    const float* __restrict__ Yin, const float* __restrict__ Zin,
    float* __restrict__ Yout, float* __restrict__ Zout)
{
    __shared__ float Ys[128][132];
    __shared__ float Zs[128][132];
    __shared__ float Ts[128][16];
    const int bid = blockIdx.x;
    const int g = bid >> 3;
    const int sl = bid & 7;
    const int J0 = sl * 16;
    const int t = threadIdx.x;
    const float* Yg = Yin + (size_t)g * GD * GD;
    const float* Zg = Zin + (size_t)g * GD * GD;
#pragma unroll
    for (int k = 0; k < 16; ++k) {
        int q = t + 256 * k;
        int row = q >> 5, c4 = q & 31;
        *(float4*)&Ys[row][c4 * 4] = *(const float4*)(Yg + (size_t)q * 4);
        *(float4*)&Zs[row][c4 * 4] = *(const float4*)(Zg + (size_t)q * 4);
    }
    __syncthreads();
    const int i = t >> 1;
    const int jb = (t & 1) * 8;

    float accT[8];
#pragma unroll
    for (int q = 0; q < 8; ++q) accT[q] = 0.f;
    for (int k4 = 0; k4 < 32; ++k4) {
        float4 zv = *(const float4*)&Zs[i][k4 * 4];
        float zz[4] = {zv.x, zv.y, zv.z, zv.w};
#pragma unroll
        for (int e = 0; e < 4; ++e) {
            const int k = k4 * 4 + e;
            float4 y0 = *(const float4*)&Ys[k][J0 + jb];
            float4 y1 = *(const float4*)&Ys[k][J0 + jb + 4];
            float yy[8] = {y0.x, y0.y, y0.z, y0.w, y1.x, y1.y, y1.z, y1.w};
#pragma unroll
            for (int q = 0; q < 8; ++q) accT[q] = fmaf(zz[e], yy[q], accT[q]);
        }
    }
#pragma unroll
    for (int q = 0; q < 8; ++q) Ts[i][jb + q] = accT[q];
    __syncthreads();

    float ay[8], az[8];
#pragma unroll
    for (int q = 0; q < 8; ++q) { ay[q] = 0.f; az[q] = 0.f; }
    for (int k4 = 0; k4 < 32; ++k4) {
        float4 yv = *(const float4*)&Ys[i][k4 * 4];
        float4 zv = *(const float4*)&Zs[i][k4 * 4];
        float yy[4] = {yv.x, yv.y, yv.z, yv.w};
        float zz[4] = {zv.x, zv.y, zv.z, zv.w};
#pragma unroll
        for (int e = 0; e < 4; ++e) {
            const int k = k4 * 4 + e;
            float4 t0 = *(const float4*)&Ts[k][jb];
            float4 t1 = *(const float4*)&Ts[k][jb + 4];
            float tt[8] = {t0.x, t0.y, t0.z, t0.w, t1.x, t1.y, t1.z, t1.w};
#pragma unroll
            for (int q = 0; q < 8; ++q) {
                ay[q] = fmaf(yy[e], tt[q], ay[q]);
                az[q] = fmaf(zz[e], tt[q], az[q]);
            }
        }
    }
    float4 yc0 = *(const float4*)&Ys[i][J0 + jb];
    float4 yc1 = *(const float4*)&Ys[i][J0 + jb + 4];
    float4 zc0 = *(const float4*)&Zs[i][J0 + jb];
    float4 zc1 = *(const float4*)&Zs[i][J0 + jb + 4];
    float* Yo = Yout + (size_t)g * GD * GD + (size_t)i * GD + J0 + jb;
    float* Zo = Zout + (size_t)g * GD * GD + (size_t)i * GD + J0 + jb;
    *(float4*)(Yo)     = make_float4(1.5f*yc0.x - 0.5f*ay[0], 1.5f*yc0.y - 0.5f*ay[1],
                                     1.5f*yc0.z - 0.5f*ay[2], 1.5f*yc0.w - 0.5f*ay[3]);
    *(float4*)(Yo + 4) = make_float4(1.5f*yc1.x - 0.5f*ay[4], 1.5f*yc1.y - 0.5f*ay[5],
                                     1.5f*yc1.z - 0.5f*ay[6], 1.5f*yc1.w - 0.5f*ay[7]);
    *(float4*)(Zo)     = make_float4(1.5f*zc0.x - 0.5f*az[0], 1.5f*zc0.y - 0.5f*az[1],
                                     1.5f*zc0.z - 0.5f*az[2], 1.5f*zc0.w - 0.5f*az[3]);
    *(float4*)(Zo + 4) = make_float4(1.5f*zc1.x - 0.5f*az[4], 1.5f*zc1.y - 0.5f*az[5],
                                     1.5f*zc1.z - 0.5f*az[6], 1.5f*zc1.w - 0.5f*az[7]);
}

// ============ K5: WT = (Z*rsqrt(c))^T bf16 ; muW = mu . W =====================
__global__ __launch_bounds__(256) void k_wprep(
    const float* __restrict__ Z, const float* __restrict__ scale,
    const float* __restrict__ mean,
    unsigned short* __restrict__ WT, float* __restrict__ muW)
{
    __shared__ float Zs[128][129];
    __shared__ float mu[128];
    const int g = blockIdx.x;
    const int t = threadIdx.x;
    const float sc = scale[g];
    if (t < 128) mu[t] = mean[g * GD + t];
    for (int k = 0; k < 64; ++k) {
        int e = t + 256 * k;
        Zs[e >> 7][e & 127] = Z[(size_t)g * (GD * GD) + e];
    }
    __syncthreads();
    const int n = t & 127, kh = t >> 7;
    unsigned short* o = WT + (size_t)g * (GD * GD) + (size_t)n * GD + kh * 64;
    for (int k = 0; k < 64; k += 2) {
        unsigned int pk = (unsigned int)f2bf(Zs[kh * 64 + k][n] * sc)
                        | ((unsigned int)f2bf(Zs[kh * 64 + k + 1][n] * sc) << 16);
        *(unsigned int*)(o + k) = pk;
    }
    if (t < 128) {
        float s = 0.f;
        for (int d = 0; d < 128; ++d) s = fmaf(mu[d], Zs[d][t], s);
        muW[g * GD + t] = s * sc;
    }
}

// ============ K6: out = x*W - muW; deep-ILP loads, NT stores ==================
// grid 2048 = 32 g x 64; 256 thr (4 waves); 4 chunks x 64 rows per block.
__global__ __launch_bounds__(256) void k_apply(
    const float* __restrict__ x, const unsigned short* __restrict__ WT,
    const float* __restrict__ muW, float* __restrict__ out)
{
    const int bid = blockIdx.x;
    const int g = bid >> 6, rbo = bid & 63;
    const int t = threadIdx.x;
    const int lane = t & 63, w = t >> 6;
    const int lm = lane & 15, lk = lane >> 4;
    const int nh = w >> 1;              // n-half (64 cols)
    const int m0w = (w & 1) * 32;       // row offset within 64-row chunk

    bf16x8 Wf[4][4];
    {
        const unsigned short* wg = WT + (size_t)g * (GD * GD);
#pragma unroll
        for (int ni = 0; ni < 4; ++ni)
#pragma unroll
            for (int ks = 0; ks < 4; ++ks)
                Wf[ni][ks] = *(const bf16x8*)(wg
                    + (size_t)(nh * 64 + ni * 16 + lm) * GD + ks * 32 + lk * 8);
    }
    float mw[4];
#pragma unroll
    for (int ni = 0; ni < 4; ++ni) mw[ni] = muW[g * GD + nh * 64 + ni * 16 + lm];

    for (int c = 0; c < 4; ++c) {
        const int row0 = rbo * 256 + c * 64;
        const float* ab = x + (size_t)(row0 + m0w) * NCOLS + g * GD;

        // issue ALL 16 loads (static indices -> registers, deep MLP)
        float4 u[16];
#pragma unroll
        for (int ks = 0; ks < 4; ++ks) {
            const float* p0 = ab + (size_t)lm * NCOLS + ks * 32 + lk * 8;
            u[ks * 4 + 0] = *(const float4*)(p0);
            u[ks * 4 + 1] = *(const float4*)(p0 + 4);
            u[ks * 4 + 2] = *(const float4*)(p0 + (size_t)16 * NCOLS);
            u[ks * 4 + 3] = *(const float4*)(p0 + (size_t)16 * NCOLS + 4);
        }

        f32x4 acc[2][4];
#pragma unroll
        for (int mi = 0; mi < 2; ++mi)
#pragma unroll
            for (int ni = 0; ni < 4; ++ni) acc[mi][ni] = (f32x4){0.f, 0.f, 0.f, 0.f};

#pragma unroll
        for (int ks = 0; ks < 4; ++ks) {
            float4 q0 = u[ks * 4 + 0], q1 = u[ks * 4 + 1];
            float4 q2 = u[ks * 4 + 2], q3 = u[ks * 4 + 3];
            bf16x8 a0, a1;
            a0[0] = (short)f2bf(q0.x); a0[1] = (short)f2bf(q0.y);
            a0[2] = (short)f2bf(q0.z); a0[3] = (short)f2bf(q0.w);
            a0[4] = (short)f2bf(q1.x); a0[5] = (short)f2bf(q1.y);
            a0[6] = (short)f2bf(q1.z); a0[7] = (short)f2bf(q1.w);
            a1[0] = (short)f2bf(q2.x); a1[1] = (short)f2bf(q2.y);
            a1[2] = (short)f2bf(q2.z); a1[3] = (short)f2bf(q2.w);
            a1[4] = (short)f2bf(q3.x); a1[5] = (short)f2bf(q3.y);
            a1[6] = (short)f2bf(q3.z); a1[7] = (short)f2bf(q3.w);
#pragma unroll
            for (int ni = 0; ni < 4; ++ni) {
                acc[0][ni] = __builtin_amdgcn_mfma_f32_16x16x32_bf16(
                    a0, Wf[ni][ks], acc[0][ni], 0, 0, 0);
                acc[1][ni] = __builtin_amdgcn_mfma_f32_16x16x32_bf16(
                    a1, Wf[ni][ks], acc[1][ni], 0, 0, 0);
            }
        }

        float* ob = out + (size_t)(row0 + m0w) * NCOLS + g * GD + nh * 64;
#pragma unroll
        for (int mi = 0; mi < 2; ++mi)
#pragma unroll
            for (int ni = 0; ni < 4; ++ni)
#pragma unroll
                for (int r = 0; r < 4; ++r)
                    __builtin_nontemporal_store(
                        acc[mi][ni][r] - mw[ni],
                        ob + (size_t)(mi * 16 + lk * 4 + r) * NCOLS + ni * 16 + lm);
    }
}

extern "C" void kernel_launch(void* const* d_in, const int* in_sizes, int n_in,
                              void* d_out, int out_size, void* d_ws, size_t ws_size,
                              hipStream_t stream) {
    const float* x = (const float*)d_in[0];
    float* out = (float*)d_out;
    float* ws = (float*)d_ws;

    float* xtx   = ws;                                    // 8,388,608 f
    float* ps    = xtx + (size_t)NG * NPC * GD * GD;      // region 2,097,152 f
    float* mean  = ps + (size_t)512 * NCOLS;              // 4,096
    float* scale = mean + NCOLS;                          // 32
    float* Cbuf  = scale + 32;                            // 524,288
    float* Ya    = Cbuf + (size_t)NG * GD * GD;
    float* Za    = Ya + (size_t)NG * GD * GD;
    float* Yb    = Za + (size_t)NG * GD * GD;
    float* Zb    = Yb + (size_t)NG * GD * GD;
    float* muW   = Zb + (size_t)NG * GD * GD;             // 4,096
    unsigned short* WT = (unsigned short*)(muW + NCOLS);  // 4 MB
    unsigned short* xT = WT + (size_t)NG * GD * GD;       // 128 MB

    k_pack<<<NG * NPC * 2, 256, 0, stream>>>(x, xT, ps);
    k_mean<<<NCOLS / 256, 256, 0, stream>>>(ps, mean);
    k_cov<<<NG * NPC, 256, 0, stream>>>(xT, xtx);
    k_covreduce<<<NG * NPC, 256, 0, stream>>>(xtx, mean, Cbuf);
    k_prep<<<NG, 256, 0, stream>>>(Cbuf, scale, Ya, Za);
    for (int it = 0; it < 6; ++it) {
        if ((it & 1) == 0)
            k_ns_iter<<<NG * 8, 256, 0, stream>>>(Ya, Za, Yb, Zb);
        else
            k_ns_iter<<<NG * 8, 256, 0, stream>>>(Yb, Zb, Ya, Za);
    }
    k_wprep<<<NG, 256, 0, stream>>>(Za, scale, mean, WT, muW);
    k_apply<<<NG * 64, 256, 0, stream>>>(x, WT, muW, out);
}

// Round 7
// 380.655 us; speedup vs baseline: 2.9387x; 1.1745x over previous
//
#include <hip/hip_runtime.h>
#include <cstddef>

#define NROWS 16384
#define NCOLS 4096
#define NG 32
#define GD 128
#define NPC 16              // K-stripes (1024 samples each)

typedef float f32x4 __attribute__((ext_vector_type(4)));
typedef short bf16x8 __attribute__((ext_vector_type(8)));

__device__ inline unsigned short f2bf(float f) {
    unsigned int u = __builtin_bit_cast(unsigned int, f);
    u += 0x7fffu + ((u >> 16) & 1u);
    return (unsigned short)(u >> 16);
}

// ============ K1: fused load+transpose+bf16 MFMA partial X^T X + col sums =====
// grid 512 = 32 g x 16 stripes; 256 thr (4 waves); 1024 rows/block.
// LDS row stride 42 bf16 (84 B = 21 dw): frag reads conflict-free, writes ~4-way.
__global__ __launch_bounds__(256) void k_cov(
    const float* __restrict__ x, float* __restrict__ xtx, float* __restrict__ ps)
{
    __shared__ unsigned short xt[2][128][42];
    __shared__ float red[4][128];
    const int bid = blockIdx.x;
    const int g = bid >> 4, p = bid & 15;
    const int t = threadIdx.x;
    const int f2 = t & 63;          // feature pair 0..63
    const int w = t >> 6;           // wave id (also row-eighth for loads)
    const int lane = t & 63;
    const int lm = lane & 15, lk = lane >> 4;
    const float* xb = x + (size_t)(p * 1024) * NCOLS + g * GD + 2 * f2;

    float csum0 = 0.f, csum1 = 0.f;
    f32x4 acc[2][8];
#pragma unroll
    for (int mi = 0; mi < 2; ++mi)
#pragma unroll
        for (int ni = 0; ni < 8; ++ni) acc[mi][ni] = (f32x4){0.f, 0.f, 0.f, 0.f};

    float2 v[8];
#define CLOAD(CC) \
    _Pragma("unroll") for (int i = 0; i < 8; ++i) \
        v[i] = *(const float2*)(xb + (size_t)((CC) * 32 + w * 8 + i) * NCOLS);
#define CWRITE(BUF) { \
    bf16x8 h0, h1; \
    _Pragma("unroll") for (int i = 0; i < 8; ++i) { \
        csum0 += v[i].x; csum1 += v[i].y; \
        h0[i] = (short)f2bf(v[i].x); h1[i] = (short)f2bf(v[i].y); } \
    *(bf16x8*)&xt[BUF][2 * f2][w * 8] = h0; \
    *(bf16x8*)&xt[BUF][2 * f2 + 1][w * 8] = h1; }

    CLOAD(0);
    CWRITE(0);
    __syncthreads();

    for (int c = 0; c < 32; ++c) {
        const int cur = c & 1;
        if (c < 31) { CLOAD(c + 1); }
        // static-named fragments (rule #20: no runtime-indexed frag arrays)
        bf16x8 A0 = *(const bf16x8*)&xt[cur][w * 32 + lm][lk * 8];
        bf16x8 A1 = *(const bf16x8*)&xt[cur][w * 32 + 16 + lm][lk * 8];
        bf16x8 B[8];
#pragma unroll
        for (int n = 0; n < 8; ++n)
            B[n] = *(const bf16x8*)&xt[cur][n * 16 + lm][lk * 8];
#pragma unroll
        for (int n = 0; n < 8; ++n) {
            acc[0][n] = __builtin_amdgcn_mfma_f32_16x16x32_bf16(A0, B[n], acc[0][n], 0, 0, 0);
            acc[1][n] = __builtin_amdgcn_mfma_f32_16x16x32_bf16(A1, B[n], acc[1][n], 0, 0, 0);
        }
        if (c < 31) { CWRITE(cur ^ 1); }
        __syncthreads();
    }
#undef CLOAD
#undef CWRITE

    float* ob = xtx + (size_t)bid * (GD * GD);
#pragma unroll
    for (int mi = 0; mi < 2; ++mi)
#pragma unroll
        for (int ni = 0; ni < 8; ++ni) {
            const int i0 = w * 32 + mi * 16 + lk * 4;
            const int j = ni * 16 + lm;
#pragma unroll
            for (int r = 0; r < 4; ++r)
                ob[(size_t)(i0 + r) * GD + j] = acc[mi][ni][r];
        }
    red[w][2 * f2] = csum0;
    red[w][2 * f2 + 1] = csum1;
    __syncthreads();
    if (t < 128) {
        float s = 0.f;
#pragma unroll
        for (int r = 0; r < 4; ++r) s += red[r][t];
        ps[(size_t)bid * GD + t] = s;
    }
}

// ============ K0b: reduce partial colsums -> mean ==============================
__global__ __launch_bounds__(256) void k_mean(
    const float* __restrict__ ps, float* __restrict__ mean)
{
    const int col = blockIdx.x * 256 + threadIdx.x;
    const int g = col >> 7, d = col & 127;
    float s = 0.f;
#pragma unroll
    for (int p = 0; p < NPC; ++p) s += ps[(size_t)(g * NPC + p) * GD + d];
    mean[col] = s * (1.0f / (float)NROWS);
}

// ============ K2: reduce partials -> C (mean-corrected) =======================
__global__ __launch_bounds__(256) void k_covreduce(
    const float* __restrict__ xtx, const float* __restrict__ mean,
    float* __restrict__ C)
{
    __shared__ float mu[128];
    const int bid = blockIdx.x;
    const int g = bid >> 4, s = bid & 15;
    const int t = threadIdx.x;
    if (t < 128) mu[t] = mean[g * GD + t];
    __syncthreads();
    const int e = s * 1024 + t * 4;
    const int i = e >> 7, j = e & 127;
    float4 sum = make_float4(0.f, 0.f, 0.f, 0.f);
#pragma unroll
    for (int p = 0; p < NPC; ++p) {
        const float4 vv = *(const float4*)(xtx + ((size_t)(g * NPC + p) << 14) + e);
        sum.x += vv.x; sum.y += vv.y; sum.z += vv.z; sum.w += vv.w;
    }
    const float inv = 1.0f / (float)(NROWS - 1);
    const float mi2 = (float)NROWS * mu[i];
    float4 r;
    r.x = (sum.x - mi2 * mu[j + 0]) * inv;
    r.y = (sum.y - mi2 * mu[j + 1]) * inv;
    r.z = (sum.z - mi2 * mu[j + 2]) * inv;
    r.w = (sum.w - mi2 * mu[j + 3]) * inv;
    *(float4*)(C + (size_t)g * (GD * GD) + e) = r;
}

// ============ K3: Gershgorin scale + Y0/Z0 ====================================
__global__ __launch_bounds__(256) void k_prep(
    const float* __restrict__ Cg, float* __restrict__ scale,
    float* __restrict__ Y0, float* __restrict__ Z0)
{
    __shared__ float Cs[128][129];
    __shared__ float rs[128];
    __shared__ float sinv[1];
    const int g = blockIdx.x;
    const int t = threadIdx.x;
    for (int k = 0; k < 64; ++k) {
        int e = t + 256 * k;
        Cs[e >> 7][e & 127] = Cg[(size_t)g * (GD * GD) + e];
    }
    __syncthreads();
    if (t < 128) {
        float s = 0.f;
        for (int i = 0; i < 128; ++i) s += fabsf(Cs[i][t]);
        rs[t] = s;
    }
    __syncthreads();
    if (t == 0) {
        float up = 0.f, lo = 1e30f;
        for (int i = 0; i < 128; ++i) {
            up = fmaxf(up, rs[i]);
            lo = fminf(lo, 2.0f * Cs[i][i] - rs[i]);
        }
        float c = 0.5f * (up + fmaxf(lo, 0.0f));
        c = fmaxf(c, 1e-20f);
        sinv[0] = 1.0f / c;
        scale[g] = rsqrtf(c);
    }
    __syncthreads();
    const float invc = sinv[0];
    for (int k = 0; k < 64; ++k) {
        int e = t + 256 * k;
        int i = e >> 7, j = e & 127;
        Y0[(size_t)g * (GD * GD) + e] = Cs[i][j] * invc;
        Z0[(size_t)g * (GD * GD) + e] = (i == j) ? 1.0f : 0.0f;
    }
}

// ============ K4: Newton-Schulz iteration (fp32) ==============================
__global__ __launch_bounds__(256) void k_ns_iter(
    const float* __restrict__ Yin, const float* __restrict__ Zin,
    float* __restrict__ Yout, float* __restrict__ Zout)
{
    __shared__ float Ys[128][132];
    __shared__ float Zs[128][132];
    __shared__ float Ts[128][16];
    const int bid = blockIdx.x;
    const int g = bid >> 3;
    const int sl = bid & 7;
    const int J0 = sl * 16;
    const int t = threadIdx.x;
    const float* Yg = Yin + (size_t)g * GD * GD;
    const float* Zg = Zin + (size_t)g * GD * GD;
#pragma unroll
    for (int k = 0; k < 16; ++k) {
        int q = t + 256 * k;
        int row = q >> 5, c4 = q & 31;
        *(float4*)&Ys[row][c4 * 4] = *(const float4*)(Yg + (size_t)q * 4);
        *(float4*)&Zs[row][c4 * 4] = *(const float4*)(Zg + (size_t)q * 4);
    }
    __syncthreads();
    const int i = t >> 1;
    const int jb = (t & 1) * 8;

    float accT[8];
#pragma unroll
    for (int q = 0; q < 8; ++q) accT[q] = 0.f;
    for (int k4 = 0; k4 < 32; ++k4) {
        float4 zv = *(const float4*)&Zs[i][k4 * 4];
        float zz[4] = {zv.x, zv.y, zv.z, zv.w};
#pragma unroll
        for (int e = 0; e < 4; ++e) {
            const int k = k4 * 4 + e;
            float4 y0 = *(const float4*)&Ys[k][J0 + jb];
            float4 y1 = *(const float4*)&Ys[k][J0 + jb + 4];
            float yy[8] = {y0.x, y0.y, y0.z, y0.w, y1.x, y1.y, y1.z, y1.w};
#pragma unroll
            for (int q = 0; q < 8; ++q) accT[q] = fmaf(zz[e], yy[q], accT[q]);
        }
    }
#pragma unroll
    for (int q = 0; q < 8; ++q) Ts[i][jb + q] = accT[q];
    __syncthreads();

    float ay[8], az[8];
#pragma unroll
    for (int q = 0; q < 8; ++q) { ay[q] = 0.f; az[q] = 0.f; }
    for (int k4 = 0; k4 < 32; ++k4) {
        float4 yv = *(const float4*)&Ys[i][k4 * 4];
        float4 zv = *(const float4*)&Zs[i][k4 * 4];
        float yy[4] = {yv.x, yv.y, yv.z, yv.w};
        float zz[4] = {zv.x, zv.y, zv.z, zv.w};
#pragma unroll
        for (int e = 0; e < 4; ++e) {
            const int k = k4 * 4 + e;
            float4 t0 = *(const float4*)&Ts[k][jb];
            float4 t1 = *(const float4*)&Ts[k][jb + 4];
            float tt[8] = {t0.x, t0.y, t0.z, t0.w, t1.x, t1.y, t1.z, t1.w};
#pragma unroll
            for (int q = 0; q < 8; ++q) {
                ay[q] = fmaf(yy[e], tt[q], ay[q]);
                az[q] = fmaf(zz[e], tt[q], az[q]);
            }
        }
    }
    float4 yc0 = *(const float4*)&Ys[i][J0 + jb];
    float4 yc1 = *(const float4*)&Ys[i][J0 + jb + 4];
    float4 zc0 = *(const float4*)&Zs[i][J0 + jb];
    float4 zc1 = *(const float4*)&Zs[i][J0 + jb + 4];
    float* Yo = Yout + (size_t)g * GD * GD + (size_t)i * GD + J0 + jb;
    float* Zo = Zout + (size_t)g * GD * GD + (size_t)i * GD + J0 + jb;
    *(float4*)(Yo)     = make_float4(1.5f*yc0.x - 0.5f*ay[0], 1.5f*yc0.y - 0.5f*ay[1],
                                     1.5f*yc0.z - 0.5f*ay[2], 1.5f*yc0.w - 0.5f*ay[3]);
    *(float4*)(Yo + 4) = make_float4(1.5f*yc1.x - 0.5f*ay[4], 1.5f*yc1.y - 0.5f*ay[5],
                                     1.5f*yc1.z - 0.5f*ay[6], 1.5f*yc1.w - 0.5f*ay[7]);
    *(float4*)(Zo)     = make_float4(1.5f*zc0.x - 0.5f*az[0], 1.5f*zc0.y - 0.5f*az[1],
                                     1.5f*zc0.z - 0.5f*az[2], 1.5f*zc0.w - 0.5f*az[3]);
    *(float4*)(Zo + 4) = make_float4(1.5f*zc1.x - 0.5f*az[4], 1.5f*zc1.y - 0.5f*az[5],
                                     1.5f*zc1.z - 0.5f*az[6], 1.5f*zc1.w - 0.5f*az[7]);
}

// ============ K5: WT = (Z*rsqrt(c))^T bf16 ; muW = mu . W =====================
__global__ __launch_bounds__(256) void k_wprep(
    const float* __restrict__ Z, const float* __restrict__ scale,
    const float* __restrict__ mean,
    unsigned short* __restrict__ WT, float* __restrict__ muW)
{
    __shared__ float Zs[128][129];
    __shared__ float mu[128];
    const int g = blockIdx.x;
    const int t = threadIdx.x;
    const float sc = scale[g];
    if (t < 128) mu[t] = mean[g * GD + t];
    for (int k = 0; k < 64; ++k) {
        int e = t + 256 * k;
        Zs[e >> 7][e & 127] = Z[(size_t)g * (GD * GD) + e];
    }
    __syncthreads();
    const int n = t & 127, kh = t >> 7;
    unsigned short* o = WT + (size_t)g * (GD * GD) + (size_t)n * GD + kh * 64;
    for (int k = 0; k < 64; k += 2) {
        unsigned int pk = (unsigned int)f2bf(Zs[kh * 64 + k][n] * sc)
                        | ((unsigned int)f2bf(Zs[kh * 64 + k + 1][n] * sc) << 16);
        *(unsigned int*)(o + k) = pk;
    }
    if (t < 128) {
        float s = 0.f;
        for (int d = 0; d < 128; ++d) s = fmaf(mu[d], Zs[d][t], s);
        muW[g * GD + t] = s * sc;
    }
}

// ============ K6: out = x*W - muW; cross-chunk pipelined loads, NT stores =====
// grid 2048 = 32 g x 64; 256 thr (4 waves); 4 chunks x 64 rows per block.
__global__ __launch_bounds__(256) void k_apply(
    const float* __restrict__ x, const unsigned short* __restrict__ WT,
    const float* __restrict__ muW, float* __restrict__ out)
{
    const int bid = blockIdx.x;
    const int g = bid >> 6, rbo = bid & 63;
    const int t = threadIdx.x;
    const int lane = t & 63, w = t >> 6;
    const int lm = lane & 15, lk = lane >> 4;
    const int nh = w >> 1;              // n-half (64 cols)
    const int m0w = (w & 1) * 32;       // row offset within 64-row chunk

    bf16x8 Wf[4][4];
    {
        const unsigned short* wg = WT + (size_t)g * (GD * GD);
#pragma unroll
        for (int ni = 0; ni < 4; ++ni)
#pragma unroll
            for (int ks = 0; ks < 4; ++ks)
                Wf[ni][ks] = *(const bf16x8*)(wg
                    + (size_t)(nh * 64 + ni * 16 + lm) * GD + ks * 32 + lk * 8);
    }
    float mw[4];
#pragma unroll
    for (int ni = 0; ni < 4; ++ni) mw[ni] = muW[g * GD + nh * 64 + ni * 16 + lm];

    float4 uA[16], uB[16];

#define ALD(U, C) { \
    const float* ab_ = x + (size_t)(rbo * 256 + (C) * 64 + m0w) * NCOLS + g * GD; \
    _Pragma("unroll") for (int ks = 0; ks < 4; ++ks) { \
        const float* p0_ = ab_ + (size_t)lm * NCOLS + ks * 32 + lk * 8; \
        U[ks * 4 + 0] = *(const float4*)(p0_); \
        U[ks * 4 + 1] = *(const float4*)(p0_ + 4); \
        U[ks * 4 + 2] = *(const float4*)(p0_ + (size_t)16 * NCOLS); \
        U[ks * 4 + 3] = *(const float4*)(p0_ + (size_t)16 * NCOLS + 4); } }

#define ACS(U, C) { \
    f32x4 acc[2][4]; \
    _Pragma("unroll") for (int mi = 0; mi < 2; ++mi) \
        _Pragma("unroll") for (int ni = 0; ni < 4; ++ni) \
            acc[mi][ni] = (f32x4){0.f, 0.f, 0.f, 0.f}; \
    _Pragma("unroll") for (int ks = 0; ks < 4; ++ks) { \
        float4 q0 = U[ks * 4 + 0], q1 = U[ks * 4 + 1]; \
        float4 q2 = U[ks * 4 + 2], q3 = U[ks * 4 + 3]; \
        bf16x8 a0, a1; \
        a0[0] = (short)f2bf(q0.x); a0[1] = (short)f2bf(q0.y); \
        a0[2] = (short)f2bf(q0.z); a0[3] = (short)f2bf(q0.w); \
        a0[4] = (short)f2bf(q1.x); a0[5] = (short)f2bf(q1.y); \
        a0[6] = (short)f2bf(q1.z); a0[7] = (short)f2bf(q1.w); \
        a1[0] = (short)f2bf(q2.x); a1[1] = (short)f2bf(q2.y); \
        a1[2] = (short)f2bf(q2.z); a1[3] = (short)f2bf(q2.w); \
        a1[4] = (short)f2bf(q3.x); a1[5] = (short)f2bf(q3.y); \
        a1[6] = (short)f2bf(q3.z); a1[7] = (short)f2bf(q3.w); \
        _Pragma("unroll") for (int ni = 0; ni < 4; ++ni) { \
            acc[0][ni] = __builtin_amdgcn_mfma_f32_16x16x32_bf16(a0, Wf[ni][ks], acc[0][ni], 0, 0, 0); \
            acc[1][ni] = __builtin_amdgcn_mfma_f32_16x16x32_bf16(a1, Wf[ni][ks], acc[1][ni], 0, 0, 0); } } \
    float* ob_ = out + (size_t)(rbo * 256 + (C) * 64 + m0w) * NCOLS + g * GD + nh * 64; \
    _Pragma("unroll") for (int mi = 0; mi < 2; ++mi) \
        _Pragma("unroll") for (int ni = 0; ni < 4; ++ni) \
            _Pragma("unroll") for (int r = 0; r < 4; ++r) \
                __builtin_nontemporal_store( \
                    acc[mi][ni][r] - mw[ni], \
                    ob_ + (size_t)(mi * 16 + lk * 4 + r) * NCOLS + ni * 16 + lm); }

    ALD(uA, 0);
    ALD(uB, 1);
    ACS(uA, 0);
    ALD(uA, 2);
    ACS(uB, 1);
    ALD(uB, 3);
    ACS(uA, 2);
    ACS(uB, 3);
#undef ALD
#undef ACS
}

extern "C" void kernel_launch(void* const* d_in, const int* in_sizes, int n_in,
                              void* d_out, int out_size, void* d_ws, size_t ws_size,
                              hipStream_t stream) {
    const float* x = (const float*)d_in[0];
    float* out = (float*)d_out;
    float* ws = (float*)d_ws;

    float* xtx   = ws;                                    // 8,388,608 f
    float* ps    = xtx + (size_t)NG * NPC * GD * GD;      // 65,536 f
    float* mean  = ps + (size_t)NG * NPC * GD;            // 4,096
    float* scale = mean + NCOLS;                          // 32
    float* Cbuf  = scale + 32;                            // 524,288
    float* Ya    = Cbuf + (size_t)NG * GD * GD;
    float* Za    = Ya + (size_t)NG * GD * GD;
    float* Yb    = Za + (size_t)NG * GD * GD;
    float* Zb    = Yb + (size_t)NG * GD * GD;
    float* muW   = Zb + (size_t)NG * GD * GD;             // 4,096
    unsigned short* WT = (unsigned short*)(muW + NCOLS);  // 4 MB

    k_cov<<<NG * NPC, 256, 0, stream>>>(x, xtx, ps);
    k_mean<<<NCOLS / 256, 256, 0, stream>>>(ps, mean);
    k_covreduce<<<NG * NPC, 256, 0, stream>>>(xtx, mean, Cbuf);
    k_prep<<<NG, 256, 0, stream>>>(Cbuf, scale, Ya, Za);
    for (int it = 0; it < 6; ++it) {
        if ((it & 1) == 0)
            k_ns_iter<<<NG * 8, 256, 0, stream>>>(Ya, Za, Yb, Zb);
        else
            k_ns_iter<<<NG * 8, 256, 0, stream>>>(Yb, Zb, Ya, Za);
    }
    k_wprep<<<NG, 256, 0, stream>>>(Za, scale, mean, WT, muW);
    k_apply<<<NG * 64, 256, 0, stream>>>(x, WT, muW, out);
}

// Round 8
// 353.390 us; speedup vs baseline: 3.1655x; 1.0772x over previous
//
#include <hip/hip_runtime.h>
#include <cstddef>

#define NROWS 16384
#define NCOLS 4096
#define NG 32
#define GD 128
#define NPC 16              // K-stripes (1024 samples each)

typedef float f32x4 __attribute__((ext_vector_type(4)));
typedef short bf16x8 __attribute__((ext_vector_type(8)));

__device__ inline unsigned short f2bf(float f) {
    unsigned int u = __builtin_bit_cast(unsigned int, f);
    u += 0x7fffu + ((u >> 16) & 1u);
    return (unsigned short)(u >> 16);
}

// ============ K1: fused load+transpose+bf16 MFMA partial X^T X + col sums =====
// Also emits row-major bf16 copy xhi[g][n][128] (free: values already in regs).
// grid 512 = 32 g x 16 stripes; 256 thr (4 waves); 1024 rows/block.
__global__ __launch_bounds__(256) void k_cov(
    const float* __restrict__ x, float* __restrict__ xtx, float* __restrict__ ps,
    unsigned short* __restrict__ xhi)
{
    __shared__ unsigned short xt[2][128][42];
    __shared__ float red[4][128];
    const int bid = blockIdx.x;
    const int g = bid >> 4, p = bid & 15;
    const int t = threadIdx.x;
    const int f2 = t & 63;          // feature pair 0..63 (== lane)
    const int w = t >> 6;           // wave id (also row-eighth for loads)
    const int lane = t & 63;
    const int lm = lane & 15, lk = lane >> 4;
    const float* xb = x + (size_t)(p * 1024) * NCOLS + g * GD + 2 * f2;
    // row-major bf16 output base for this thread's column pair
    unsigned int* xo = (unsigned int*)(xhi
        + ((size_t)g * NROWS + p * 1024 + w * 8) * GD + 2 * f2);

    float csum0 = 0.f, csum1 = 0.f;
    f32x4 acc[2][8];
#pragma unroll
    for (int mi = 0; mi < 2; ++mi)
#pragma unroll
        for (int ni = 0; ni < 8; ++ni) acc[mi][ni] = (f32x4){0.f, 0.f, 0.f, 0.f};

    float2 v[8];
#define CLOAD(CC) \
    _Pragma("unroll") for (int i = 0; i < 8; ++i) \
        v[i] = *(const float2*)(xb + (size_t)((CC) * 32 + w * 8 + i) * NCOLS);
#define CWRITE(BUF, CC) { \
    bf16x8 h0, h1; \
    _Pragma("unroll") for (int i = 0; i < 8; ++i) { \
        csum0 += v[i].x; csum1 += v[i].y; \
        unsigned int b0 = f2bf(v[i].x), b1 = f2bf(v[i].y); \
        h0[i] = (short)b0; h1[i] = (short)b1; \
        xo[(size_t)((CC) * 32 + i) * 64] = b0 | (b1 << 16); } \
    *(bf16x8*)&xt[BUF][2 * f2][w * 8] = h0; \
    *(bf16x8*)&xt[BUF][2 * f2 + 1][w * 8] = h1; }

    CLOAD(0);
    CWRITE(0, 0);
    __syncthreads();

    for (int c = 0; c < 32; ++c) {
        const int cur = c & 1;
        if (c < 31) { CLOAD(c + 1); }
        // static-named fragments (rule #20: no runtime-indexed frag arrays)
        bf16x8 A0 = *(const bf16x8*)&xt[cur][w * 32 + lm][lk * 8];
        bf16x8 A1 = *(const bf16x8*)&xt[cur][w * 32 + 16 + lm][lk * 8];
        bf16x8 B[8];
#pragma unroll
        for (int n = 0; n < 8; ++n)
            B[n] = *(const bf16x8*)&xt[cur][n * 16 + lm][lk * 8];
#pragma unroll
        for (int n = 0; n < 8; ++n) {
            acc[0][n] = __builtin_amdgcn_mfma_f32_16x16x32_bf16(A0, B[n], acc[0][n], 0, 0, 0);
            acc[1][n] = __builtin_amdgcn_mfma_f32_16x16x32_bf16(A1, B[n], acc[1][n], 0, 0, 0);
        }
        if (c < 31) { CWRITE(cur ^ 1, c + 1); }
        __syncthreads();
    }
#undef CLOAD
#undef CWRITE

    float* ob = xtx + (size_t)bid * (GD * GD);
#pragma unroll
    for (int mi = 0; mi < 2; ++mi)
#pragma unroll
        for (int ni = 0; ni < 8; ++ni) {
            const int i0 = w * 32 + mi * 16 + lk * 4;
            const int j = ni * 16 + lm;
#pragma unroll
            for (int r = 0; r < 4; ++r)
                ob[(size_t)(i0 + r) * GD + j] = acc[mi][ni][r];
        }
    red[w][2 * f2] = csum0;
    red[w][2 * f2 + 1] = csum1;
    __syncthreads();
    if (t < 128) {
        float s = 0.f;
#pragma unroll
        for (int r = 0; r < 4; ++r) s += red[r][t];
        ps[(size_t)bid * GD + t] = s;
    }
}

// ============ K0b: reduce partial colsums -> mean ==============================
__global__ __launch_bounds__(256) void k_mean(
    const float* __restrict__ ps, float* __restrict__ mean)
{
    const int col = blockIdx.x * 256 + threadIdx.x;
    const int g = col >> 7, d = col & 127;
    float s = 0.f;
#pragma unroll
    for (int p = 0; p < NPC; ++p) s += ps[(size_t)(g * NPC + p) * GD + d];
    mean[col] = s * (1.0f / (float)NROWS);
}

// ============ K2: reduce partials -> C (mean-corrected) =======================
__global__ __launch_bounds__(256) void k_covreduce(
    const float* __restrict__ xtx, const float* __restrict__ mean,
    float* __restrict__ C)
{
    __shared__ float mu[128];
    const int bid = blockIdx.x;
    const int g = bid >> 4, s = bid & 15;
    const int t = threadIdx.x;
    if (t < 128) mu[t] = mean[g * GD + t];
    __syncthreads();
    const int e = s * 1024 + t * 4;
    const int i = e >> 7, j = e & 127;
    float4 sum = make_float4(0.f, 0.f, 0.f, 0.f);
#pragma unroll
    for (int p = 0; p < NPC; ++p) {
        const float4 vv = *(const float4*)(xtx + ((size_t)(g * NPC + p) << 14) + e);
        sum.x += vv.x; sum.y += vv.y; sum.z += vv.z; sum.w += vv.w;
    }
    const float inv = 1.0f / (float)(NROWS - 1);
    const float mi2 = (float)NROWS * mu[i];
    float4 r;
    r.x = (sum.x - mi2 * mu[j + 0]) * inv;
    r.y = (sum.y - mi2 * mu[j + 1]) * inv;
    r.z = (sum.z - mi2 * mu[j + 2]) * inv;
    r.w = (sum.w - mi2 * mu[j + 3]) * inv;
    *(float4*)(C + (size_t)g * (GD * GD) + e) = r;
}

// ============ K3: Gershgorin scale + Y0/Z0 ====================================
__global__ __launch_bounds__(256) void k_prep(
    const float* __restrict__ Cg, float* __restrict__ scale,
    float* __restrict__ Y0, float* __restrict__ Z0)
{
    __shared__ float Cs[128][129];
    __shared__ float rs[128];
    __shared__ float sinv[1];
    const int g = blockIdx.x;
    const int t = threadIdx.x;
    for (int k = 0; k < 64; ++k) {
        int e = t + 256 * k;
        Cs[e >> 7][e & 127] = Cg[(size_t)g * (GD * GD) + e];
    }
    __syncthreads();
    if (t < 128) {
        float s = 0.f;
        for (int i = 0; i < 128; ++i) s += fabsf(Cs[i][t]);
        rs[t] = s;
    }
    __syncthreads();
    if (t == 0) {
        float up = 0.f, lo = 1e30f;
        for (int i = 0; i < 128; ++i) {
            up = fmaxf(up, rs[i]);
            lo = fminf(lo, 2.0f * Cs[i][i] - rs[i]);
        }
        float c = 0.5f * (up + fmaxf(lo, 0.0f));
        c = fmaxf(c, 1e-20f);
        sinv[0] = 1.0f / c;
        scale[g] = rsqrtf(c);
    }
    __syncthreads();
    const float invc = sinv[0];
    for (int k = 0; k < 64; ++k) {
        int e = t + 256 * k;
        int i = e >> 7, j = e & 127;
        Y0[(size_t)g * (GD * GD) + e] = Cs[i][j] * invc;
        Z0[(size_t)g * (GD * GD) + e] = (i == j) ? 1.0f : 0.0f;
    }
}

// ============ K4: Newton-Schulz iteration (fp32) ==============================
__global__ __launch_bounds__(256) void k_ns_iter(
    const float* __restrict__ Yin, const float* __restrict__ Zin,
    float* __restrict__ Yout, float* __restrict__ Zout)
{
    __shared__ float Ys[128][132];
    __shared__ float Zs[128][132];
    __shared__ float Ts[128][16];
    const int bid = blockIdx.x;
    const int g = bid >> 3;
    const int sl = bid & 7;
    const int J0 = sl * 16;
    const int t = threadIdx.x;
    const float* Yg = Yin + (size_t)g * GD * GD;
    const float* Zg = Zin + (size_t)g * GD * GD;
#pragma unroll
    for (int k = 0; k < 16; ++k) {
        int q = t + 256 * k;
        int row = q >> 5, c4 = q & 31;
        *(float4*)&Ys[row][c4 * 4] = *(const float4*)(Yg + (size_t)q * 4);
        *(float4*)&Zs[row][c4 * 4] = *(const float4*)(Zg + (size_t)q * 4);
    }
    __syncthreads();
    const int i = t >> 1;
    const int jb = (t & 1) * 8;

    float accT[8];
#pragma unroll
    for (int q = 0; q < 8; ++q) accT[q] = 0.f;
    for (int k4 = 0; k4 < 32; ++k4) {
        float4 zv = *(const float4*)&Zs[i][k4 * 4];
        float zz[4] = {zv.x, zv.y, zv.z, zv.w};
#pragma unroll
        for (int e = 0; e < 4; ++e) {
            const int k = k4 * 4 + e;
            float4 y0 = *(const float4*)&Ys[k][J0 + jb];
            float4 y1 = *(const float4*)&Ys[k][J0 + jb + 4];
            float yy[8] = {y0.x, y0.y, y0.z, y0.w, y1.x, y1.y, y1.z, y1.w};
#pragma unroll
            for (int q = 0; q < 8; ++q) accT[q] = fmaf(zz[e], yy[q], accT[q]);
        }
    }
#pragma unroll
    for (int q = 0; q < 8; ++q) Ts[i][jb + q] = accT[q];
    __syncthreads();

    float ay[8], az[8];
#pragma unroll
    for (int q = 0; q < 8; ++q) { ay[q] = 0.f; az[q] = 0.f; }
    for (int k4 = 0; k4 < 32; ++k4) {
        float4 yv = *(const float4*)&Ys[i][k4 * 4];
        float4 zv = *(const float4*)&Zs[i][k4 * 4];
        float yy[4] = {yv.x, yv.y, yv.z, yv.w};
        float zz[4] = {zv.x, zv.y, zv.z, zv.w};
#pragma unroll
        for (int e = 0; e < 4; ++e) {
            const int k = k4 * 4 + e;
            float4 t0 = *(const float4*)&Ts[k][jb];
            float4 t1 = *(const float4*)&Ts[k][jb + 4];
            float tt[8] = {t0.x, t0.y, t0.z, t0.w, t1.x, t1.y, t1.z, t1.w};
#pragma unroll
            for (int q = 0; q < 8; ++q) {
                ay[q] = fmaf(yy[e], tt[q], ay[q]);
                az[q] = fmaf(zz[e], tt[q], az[q]);
            }
        }
    }
    float4 yc0 = *(const float4*)&Ys[i][J0 + jb];
    float4 yc1 = *(const float4*)&Ys[i][J0 + jb + 4];
    float4 zc0 = *(const float4*)&Zs[i][J0 + jb];
    float4 zc1 = *(const float4*)&Zs[i][J0 + jb + 4];
    float* Yo = Yout + (size_t)g * GD * GD + (size_t)i * GD + J0 + jb;
    float* Zo = Zout + (size_t)g * GD * GD + (size_t)i * GD + J0 + jb;
    *(float4*)(Yo)     = make_float4(1.5f*yc0.x - 0.5f*ay[0], 1.5f*yc0.y - 0.5f*ay[1],
                                     1.5f*yc0.z - 0.5f*ay[2], 1.5f*yc0.w - 0.5f*ay[3]);
    *(float4*)(Yo + 4) = make_float4(1.5f*yc1.x - 0.5f*ay[4], 1.5f*yc1.y - 0.5f*ay[5],
                                     1.5f*yc1.z - 0.5f*ay[6], 1.5f*yc1.w - 0.5f*ay[7]);
    *(float4*)(Zo)     = make_float4(1.5f*zc0.x - 0.5f*az[0], 1.5f*zc0.y - 0.5f*az[1],
                                     1.5f*zc0.z - 0.5f*az[2], 1.5f*zc0.w - 0.5f*az[3]);
    *(float4*)(Zo + 4) = make_float4(1.5f*zc1.x - 0.5f*az[4], 1.5f*zc1.y - 0.5f*az[5],
                                     1.5f*zc1.z - 0.5f*az[6], 1.5f*zc1.w - 0.5f*az[7]);
}

// ============ K5: WT = (Z*rsqrt(c))^T bf16 ; muW = mu . W =====================
__global__ __launch_bounds__(256) void k_wprep(
    const float* __restrict__ Z, const float* __restrict__ scale,
    const float* __restrict__ mean,
    unsigned short* __restrict__ WT, float* __restrict__ muW)
{
    __shared__ float Zs[128][129];
    __shared__ float mu[128];
    const int g = blockIdx.x;
    const int t = threadIdx.x;
    const float sc = scale[g];
    if (t < 128) mu[t] = mean[g * GD + t];
    for (int k = 0; k < 64; ++k) {
        int e = t + 256 * k;
        Zs[e >> 7][e & 127] = Z[(size_t)g * (GD * GD) + e];
    }
    __syncthreads();
    const int n = t & 127, kh = t >> 7;
    unsigned short* o = WT + (size_t)g * (GD * GD) + (size_t)n * GD + kh * 64;
    for (int k = 0; k < 64; k += 2) {
        unsigned int pk = (unsigned int)f2bf(Zs[kh * 64 + k][n] * sc)
                        | ((unsigned int)f2bf(Zs[kh * 64 + k + 1][n] * sc) << 16);
        *(unsigned int*)(o + k) = pk;
    }
    if (t < 128) {
        float s = 0.f;
        for (int d = 0; d < 128; ++d) s = fmaf(mu[d], Zs[d][t], s);
        muW[g * GD + t] = s * sc;
    }
}

// ============ K6: out = xhi*W - muW; bf16 A-frags direct, NT stores ===========
// grid 2048 = 32 g x 64; 256 thr (4 waves); 4 chunks x 64 rows per block.
__global__ __launch_bounds__(256) void k_apply(
    const unsigned short* __restrict__ xhi, const unsigned short* __restrict__ WT,
    const float* __restrict__ muW, float* __restrict__ out)
{
    const int bid = blockIdx.x;
    const int g = bid >> 6, rbo = bid & 63;
    const int t = threadIdx.x;
    const int lane = t & 63, w = t >> 6;
    const int lm = lane & 15, lk = lane >> 4;
    const int nh = w >> 1;              // n-half (64 cols)
    const int m0w = (w & 1) * 32;       // row offset within 64-row chunk

    bf16x8 Wf[4][4];
    {
        const unsigned short* wg = WT + (size_t)g * (GD * GD);
#pragma unroll
        for (int ni = 0; ni < 4; ++ni)
#pragma unroll
            for (int ks = 0; ks < 4; ++ks)
                Wf[ni][ks] = *(const bf16x8*)(wg
                    + (size_t)(nh * 64 + ni * 16 + lm) * GD + ks * 32 + lk * 8);
    }
    float mw[4];
#pragma unroll
    for (int ni = 0; ni < 4; ++ni) mw[ni] = muW[g * GD + nh * 64 + ni * 16 + lm];

    for (int c = 0; c < 4; ++c) {
        const int row0 = rbo * 256 + c * 64;
        const unsigned short* ab = xhi
            + ((size_t)g * NROWS + row0 + m0w + lm) * GD + lk * 8;

        // 8 x 16 B loads, all static indices, issued before any MFMA
        bf16x8 u[8];
#pragma unroll
        for (int ks = 0; ks < 4; ++ks) {
            u[ks * 2 + 0] = *(const bf16x8*)(ab + ks * 32);
            u[ks * 2 + 1] = *(const bf16x8*)(ab + (size_t)16 * GD + ks * 32);
        }

        f32x4 acc[2][4];
#pragma unroll
        for (int mi = 0; mi < 2; ++mi)
#pragma unroll
            for (int ni = 0; ni < 4; ++ni) acc[mi][ni] = (f32x4){0.f, 0.f, 0.f, 0.f};

#pragma unroll
        for (int ks = 0; ks < 4; ++ks) {
#pragma unroll
            for (int ni = 0; ni < 4; ++ni) {
                acc[0][ni] = __builtin_amdgcn_mfma_f32_16x16x32_bf16(
                    u[ks * 2 + 0], Wf[ni][ks], acc[0][ni], 0, 0, 0);
                acc[1][ni] = __builtin_amdgcn_mfma_f32_16x16x32_bf16(
                    u[ks * 2 + 1], Wf[ni][ks], acc[1][ni], 0, 0, 0);
            }
        }

        float* ob = out + (size_t)(row0 + m0w) * NCOLS + g * GD + nh * 64;
#pragma unroll
        for (int mi = 0; mi < 2; ++mi)
#pragma unroll
            for (int ni = 0; ni < 4; ++ni)
#pragma unroll
                for (int r = 0; r < 4; ++r)
                    __builtin_nontemporal_store(
                        acc[mi][ni][r] - mw[ni],
                        ob + (size_t)(mi * 16 + lk * 4 + r) * NCOLS + ni * 16 + lm);
    }
}

extern "C" void kernel_launch(void* const* d_in, const int* in_sizes, int n_in,
                              void* d_out, int out_size, void* d_ws, size_t ws_size,
                              hipStream_t stream) {
    const float* x = (const float*)d_in[0];
    float* out = (float*)d_out;
    float* ws = (float*)d_ws;

    float* xtx   = ws;                                    // 8,388,608 f
    float* ps    = xtx + (size_t)NG * NPC * GD * GD;      // 65,536 f
    float* mean  = ps + (size_t)NG * NPC * GD;            // 4,096
    float* scale = mean + NCOLS;                          // 32
    float* Cbuf  = scale + 32;                            // 524,288
    float* Ya    = Cbuf + (size_t)NG * GD * GD;
    float* Za    = Ya + (size_t)NG * GD * GD;
    float* Yb    = Za + (size_t)NG * GD * GD;
    float* Zb    = Yb + (size_t)NG * GD * GD;
    float* muW   = Zb + (size_t)NG * GD * GD;             // 4,096
    unsigned short* WT  = (unsigned short*)(muW + NCOLS); // 4 MB
    unsigned short* xhi = WT + (size_t)NG * GD * GD;      // 128 MB

    k_cov<<<NG * NPC, 256, 0, stream>>>(x, xtx, ps, xhi);
    k_mean<<<NCOLS / 256, 256, 0, stream>>>(ps, mean);
    k_covreduce<<<NG * NPC, 256, 0, stream>>>(xtx, mean, Cbuf);
    k_prep<<<NG, 256, 0, stream>>>(Cbuf, scale, Ya, Za);
    for (int it = 0; it < 6; ++it) {
        if ((it & 1) == 0)
            k_ns_iter<<<NG * 8, 256, 0, stream>>>(Ya, Za, Yb, Zb);
        else
            k_ns_iter<<<NG * 8, 256, 0, stream>>>(Yb, Zb, Ya, Za);
    }
    k_wprep<<<NG, 256, 0, stream>>>(Za, scale, mean, WT, muW);
    k_apply<<<NG * 64, 256, 0, stream>>>(xhi, WT, muW, out);
}

// Round 9
// 351.793 us; speedup vs baseline: 3.1798x; 1.0045x over previous
//
#include <hip/hip_runtime.h>
#include <cstddef>

#define NROWS 16384
#define NCOLS 4096
#define NG 32
#define GD 128
#define NPC 16              // K-stripes (1024 samples each)

typedef float f32x4 __attribute__((ext_vector_type(4)));
typedef short bf16x8 __attribute__((ext_vector_type(8)));

__device__ inline unsigned short f2bf(float f) {
    unsigned int u = __builtin_bit_cast(unsigned int, f);
    u += 0x7fffu + ((u >> 16) & 1u);
    return (unsigned short)(u >> 16);
}

// ============ K1: fused load+transpose+bf16 MFMA partial X^T X + col sums =====
// Also emits row-major bf16 copy xhi[g][n][128] (free: values already in regs).
// grid 512 = 32 g x 16 stripes; 256 thr (4 waves); 1024 rows/block.
__global__ __launch_bounds__(256) void k_cov(
    const float* __restrict__ x, float* __restrict__ xtx, float* __restrict__ ps,
    unsigned short* __restrict__ xhi)
{
    __shared__ unsigned short xt[2][128][42];
    __shared__ float red[4][128];
    const int bid = blockIdx.x;
    const int g = bid >> 4, p = bid & 15;
    const int t = threadIdx.x;
    const int f2 = t & 63;          // feature pair 0..63 (== lane)
    const int w = t >> 6;           // wave id (also row-eighth for loads)
    const int lane = t & 63;
    const int lm = lane & 15, lk = lane >> 4;
    const float* xb = x + (size_t)(p * 1024) * NCOLS + g * GD + 2 * f2;
    unsigned int* xo = (unsigned int*)(xhi
        + ((size_t)g * NROWS + p * 1024 + w * 8) * GD + 2 * f2);

    float csum0 = 0.f, csum1 = 0.f;
    f32x4 acc[2][8];
#pragma unroll
    for (int mi = 0; mi < 2; ++mi)
#pragma unroll
        for (int ni = 0; ni < 8; ++ni) acc[mi][ni] = (f32x4){0.f, 0.f, 0.f, 0.f};

    float2 v[8];
#define CLOAD(CC) \
    _Pragma("unroll") for (int i = 0; i < 8; ++i) \
        v[i] = *(const float2*)(xb + (size_t)((CC) * 32 + w * 8 + i) * NCOLS);
#define CWRITE(BUF, CC) { \
    bf16x8 h0, h1; \
    _Pragma("unroll") for (int i = 0; i < 8; ++i) { \
        csum0 += v[i].x; csum1 += v[i].y; \
        unsigned int b0 = f2bf(v[i].x), b1 = f2bf(v[i].y); \
        h0[i] = (short)b0; h1[i] = (short)b1; \
        xo[(size_t)((CC) * 32 + i) * 64] = b0 | (b1 << 16); } \
    *(bf16x8*)&xt[BUF][2 * f2][w * 8] = h0; \
    *(bf16x8*)&xt[BUF][2 * f2 + 1][w * 8] = h1; }

    CLOAD(0);
    CWRITE(0, 0);
    __syncthreads();

    for (int c = 0; c < 32; ++c) {
        const int cur = c & 1;
        if (c < 31) { CLOAD(c + 1); }
        bf16x8 A0 = *(const bf16x8*)&xt[cur][w * 32 + lm][lk * 8];
        bf16x8 A1 = *(const bf16x8*)&xt[cur][w * 32 + 16 + lm][lk * 8];
        bf16x8 B[8];
#pragma unroll
        for (int n = 0; n < 8; ++n)
            B[n] = *(const bf16x8*)&xt[cur][n * 16 + lm][lk * 8];
#pragma unroll
        for (int n = 0; n < 8; ++n) {
            acc[0][n] = __builtin_amdgcn_mfma_f32_16x16x32_bf16(A0, B[n], acc[0][n], 0, 0, 0);
            acc[1][n] = __builtin_amdgcn_mfma_f32_16x16x32_bf16(A1, B[n], acc[1][n], 0, 0, 0);
        }
        if (c < 31) { CWRITE(cur ^ 1, c + 1); }
        __syncthreads();
    }
#undef CLOAD
#undef CWRITE

    float* ob = xtx + (size_t)bid * (GD * GD);
#pragma unroll
    for (int mi = 0; mi < 2; ++mi)
#pragma unroll
        for (int ni = 0; ni < 8; ++ni) {
            const int i0 = w * 32 + mi * 16 + lk * 4;
            const int j = ni * 16 + lm;
#pragma unroll
            for (int r = 0; r < 4; ++r)
                ob[(size_t)(i0 + r) * GD + j] = acc[mi][ni][r];
        }
    red[w][2 * f2] = csum0;
    red[w][2 * f2 + 1] = csum1;
    __syncthreads();
    if (t < 128) {
        float s = 0.f;
#pragma unroll
        for (int r = 0; r < 4; ++r) s += red[r][t];
        ps[(size_t)bid * GD + t] = s;
    }
}

// ============ K0b: reduce partial colsums -> mean ==============================
__global__ __launch_bounds__(256) void k_mean(
    const float* __restrict__ ps, float* __restrict__ mean)
{
    const int col = blockIdx.x * 256 + threadIdx.x;
    const int g = col >> 7, d = col & 127;
    float s = 0.f;
#pragma unroll
    for (int p = 0; p < NPC; ++p) s += ps[(size_t)(g * NPC + p) * GD + d];
    mean[col] = s * (1.0f / (float)NROWS);
}

// ============ K2: reduce partials -> C (mean-corrected) =======================
__global__ __launch_bounds__(256) void k_covreduce(
    const float* __restrict__ xtx, const float* __restrict__ mean,
    float* __restrict__ C)
{
    __shared__ float mu[128];
    const int bid = blockIdx.x;
    const int g = bid >> 4, s = bid & 15;
    const int t = threadIdx.x;
    if (t < 128) mu[t] = mean[g * GD + t];
    __syncthreads();
    const int e = s * 1024 + t * 4;
    const int i = e >> 7, j = e & 127;
    float4 sum = make_float4(0.f, 0.f, 0.f, 0.f);
#pragma unroll
    for (int p = 0; p < NPC; ++p) {
        const float4 vv = *(const float4*)(xtx + ((size_t)(g * NPC + p) << 14) + e);
        sum.x += vv.x; sum.y += vv.y; sum.z += vv.z; sum.w += vv.w;
    }
    const float inv = 1.0f / (float)(NROWS - 1);
    const float mi2 = (float)NROWS * mu[i];
    float4 r;
    r.x = (sum.x - mi2 * mu[j + 0]) * inv;
    r.y = (sum.y - mi2 * mu[j + 1]) * inv;
    r.z = (sum.z - mi2 * mu[j + 2]) * inv;
    r.w = (sum.w - mi2 * mu[j + 3]) * inv;
    *(float4*)(C + (size_t)g * (GD * GD) + e) = r;
}

// ============ K3: Gershgorin scale + Y0/Z0 ====================================
__global__ __launch_bounds__(256) void k_prep(
    const float* __restrict__ Cg, float* __restrict__ scale,
    float* __restrict__ Y0, float* __restrict__ Z0)
{
    __shared__ float Cs[128][129];
    __shared__ float rs[128];
    __shared__ float sinv[1];
    const int g = blockIdx.x;
    const int t = threadIdx.x;
    for (int k = 0; k < 64; ++k) {
        int e = t + 256 * k;
        Cs[e >> 7][e & 127] = Cg[(size_t)g * (GD * GD) + e];
    }
    __syncthreads();
    if (t < 128) {
        float s = 0.f;
        for (int i = 0; i < 128; ++i) s += fabsf(Cs[i][t]);
        rs[t] = s;
    }
    __syncthreads();
    if (t == 0) {
        float up = 0.f, lo = 1e30f;
        for (int i = 0; i < 128; ++i) {
            up = fmaxf(up, rs[i]);
            lo = fminf(lo, 2.0f * Cs[i][i] - rs[i]);
        }
        float c = 0.5f * (up + fmaxf(lo, 0.0f));
        c = fmaxf(c, 1e-20f);
        sinv[0] = 1.0f / c;
        scale[g] = rsqrtf(c);
    }
    __syncthreads();
    const float invc = sinv[0];
    for (int k = 0; k < 64; ++k) {
        int e = t + 256 * k;
        int i = e >> 7, j = e & 127;
        Y0[(size_t)g * (GD * GD) + e] = Cs[i][j] * invc;
        Z0[(size_t)g * (GD * GD) + e] = (i == j) ? 1.0f : 0.0f;
    }
}

// ============ K4: Newton-Schulz iteration (fp32) ==============================
__global__ __launch_bounds__(256) void k_ns_iter(
    const float* __restrict__ Yin, const float* __restrict__ Zin,
    float* __restrict__ Yout, float* __restrict__ Zout)
{
    __shared__ float Ys[128][132];
    __shared__ float Zs[128][132];
    __shared__ float Ts[128][16];
    const int bid = blockIdx.x;
    const int g = bid >> 3;
    const int sl = bid & 7;
    const int J0 = sl * 16;
    const int t = threadIdx.x;
    const float* Yg = Yin + (size_t)g * GD * GD;
    const float* Zg = Zin + (size_t)g * GD * GD;
#pragma unroll
    for (int k = 0; k < 16; ++k) {
        int q = t + 256 * k;
        int row = q >> 5, c4 = q & 31;
        *(float4*)&Ys[row][c4 * 4] = *(const float4*)(Yg + (size_t)q * 4);
        *(float4*)&Zs[row][c4 * 4] = *(const float4*)(Zg + (size_t)q * 4);
    }
    __syncthreads();
    const int i = t >> 1;
    const int jb = (t & 1) * 8;

    float accT[8];
#pragma unroll
    for (int q = 0; q < 8; ++q) accT[q] = 0.f;
    for (int k4 = 0; k4 < 32; ++k4) {
        float4 zv = *(const float4*)&Zs[i][k4 * 4];
        float zz[4] = {zv.x, zv.y, zv.z, zv.w};
#pragma unroll
        for (int e = 0; e < 4; ++e) {
            const int k = k4 * 4 + e;
            float4 y0 = *(const float4*)&Ys[k][J0 + jb];
            float4 y1 = *(const float4*)&Ys[k][J0 + jb + 4];
            float yy[8] = {y0.x, y0.y, y0.z, y0.w, y1.x, y1.y, y1.z, y1.w};
#pragma unroll
            for (int q = 0; q < 8; ++q) accT[q] = fmaf(zz[e], yy[q], accT[q]);
        }
    }
#pragma unroll
    for (int q = 0; q < 8; ++q) Ts[i][jb + q] = accT[q];
    __syncthreads();

    float ay[8], az[8];
#pragma unroll
    for (int q = 0; q < 8; ++q) { ay[q] = 0.f; az[q] = 0.f; }
    for (int k4 = 0; k4 < 32; ++k4) {
        float4 yv = *(const float4*)&Ys[i][k4 * 4];
        float4 zv = *(const float4*)&Zs[i][k4 * 4];
        float yy[4] = {yv.x, yv.y, yv.z, yv.w};
        float zz[4] = {zv.x, zv.y, zv.z, zv.w};
#pragma unroll
        for (int e = 0; e < 4; ++e) {
            const int k = k4 * 4 + e;
            float4 t0 = *(const float4*)&Ts[k][jb];
            float4 t1 = *(const float4*)&Ts[k][jb + 4];
            float tt[8] = {t0.x, t0.y, t0.z, t0.w, t1.x, t1.y, t1.z, t1.w};
#pragma unroll
            for (int q = 0; q < 8; ++q) {
                ay[q] = fmaf(yy[e], tt[q], ay[q]);
                az[q] = fmaf(zz[e], tt[q], az[q]);
            }
        }
    }
    float4 yc0 = *(const float4*)&Ys[i][J0 + jb];
    float4 yc1 = *(const float4*)&Ys[i][J0 + jb + 4];
    float4 zc0 = *(const float4*)&Zs[i][J0 + jb];
    float4 zc1 = *(const float4*)&Zs[i][J0 + jb + 4];
    float* Yo = Yout + (size_t)g * GD * GD + (size_t)i * GD + J0 + jb;
    float* Zo = Zout + (size_t)g * GD * GD + (size_t)i * GD + J0 + jb;
    *(float4*)(Yo)     = make_float4(1.5f*yc0.x - 0.5f*ay[0], 1.5f*yc0.y - 0.5f*ay[1],
                                     1.5f*yc0.z - 0.5f*ay[2], 1.5f*yc0.w - 0.5f*ay[3]);
    *(float4*)(Yo + 4) = make_float4(1.5f*yc1.x - 0.5f*ay[4], 1.5f*yc1.y - 0.5f*ay[5],
                                     1.5f*yc1.z - 0.5f*ay[6], 1.5f*yc1.w - 0.5f*ay[7]);
    *(float4*)(Zo)     = make_float4(1.5f*zc0.x - 0.5f*az[0], 1.5f*zc0.y - 0.5f*az[1],
                                     1.5f*zc0.z - 0.5f*az[2], 1.5f*zc0.w - 0.5f*az[3]);
    *(float4*)(Zo + 4) = make_float4(1.5f*zc1.x - 0.5f*az[4], 1.5f*zc1.y - 0.5f*az[5],
                                     1.5f*zc1.z - 0.5f*az[6], 1.5f*zc1.w - 0.5f*az[7]);
}

// ============ K5: WT = (Z*rsqrt(c))^T bf16 ; muW = mu . W =====================
__global__ __launch_bounds__(256) void k_wprep(
    const float* __restrict__ Z, const float* __restrict__ scale,
    const float* __restrict__ mean,
    unsigned short* __restrict__ WT, float* __restrict__ muW)
{
    __shared__ float Zs[128][129];
    __shared__ float mu[128];
    const int g = blockIdx.x;
    const int t = threadIdx.x;
    const float sc = scale[g];
    if (t < 128) mu[t] = mean[g * GD + t];
    for (int k = 0; k < 64; ++k) {
        int e = t + 256 * k;
        Zs[e >> 7][e & 127] = Z[(size_t)g * (GD * GD) + e];
    }
    __syncthreads();
    const int n = t & 127, kh = t >> 7;
    unsigned short* o = WT + (size_t)g * (GD * GD) + (size_t)n * GD + kh * 64;
    for (int k = 0; k < 64; k += 2) {
        unsigned int pk = (unsigned int)f2bf(Zs[kh * 64 + k][n] * sc)
                        | ((unsigned int)f2bf(Zs[kh * 64 + k + 1][n] * sc) << 16);
        *(unsigned int*)(o + k) = pk;
    }
    if (t < 128) {
        float s = 0.f;
        for (int d = 0; d < 128; ++d) s = fmaf(mu[d], Zs[d][t], s);
        muW[g * GD + t] = s * sc;
    }
}

// ============ K6: out = xhi*W - muW; bf16 A-frags direct, PLAIN stores ========
// grid 2048 = 32 g x 64; 256 thr (4 waves); 4 chunks x 64 rows per block.
__global__ __launch_bounds__(256) void k_apply(
    const unsigned short* __restrict__ xhi, const unsigned short* __restrict__ WT,
    const float* __restrict__ muW, float* __restrict__ out)
{
    const int bid = blockIdx.x;
    const int g = bid >> 6, rbo = bid & 63;
    const int t = threadIdx.x;
    const int lane = t & 63, w = t >> 6;
    const int lm = lane & 15, lk = lane >> 4;
    const int nh = w >> 1;              // n-half (64 cols)
    const int m0w = (w & 1) * 32;       // row offset within 64-row chunk

    bf16x8 Wf[4][4];
    {
        const unsigned short* wg = WT + (size_t)g * (GD * GD);
#pragma unroll
        for (int ni = 0; ni < 4; ++ni)
#pragma unroll
            for (int ks = 0; ks < 4; ++ks)
                Wf[ni][ks] = *(const bf16x8*)(wg
                    + (size_t)(nh * 64 + ni * 16 + lm) * GD + ks * 32 + lk * 8);
    }
    float mw[4];
#pragma unroll
    for (int ni = 0; ni < 4; ++ni) mw[ni] = muW[g * GD + nh * 64 + ni * 16 + lm];

    for (int c = 0; c < 4; ++c) {
        const int row0 = rbo * 256 + c * 64;
        const unsigned short* ab = xhi
            + ((size_t)g * NROWS + row0 + m0w + lm) * GD + lk * 8;

        bf16x8 u[8];
#pragma unroll
        for (int ks = 0; ks < 4; ++ks) {
            u[ks * 2 + 0] = *(const bf16x8*)(ab + ks * 32);
            u[ks * 2 + 1] = *(const bf16x8*)(ab + (size_t)16 * GD + ks * 32);
        }

        f32x4 acc[2][4];
#pragma unroll
        for (int mi = 0; mi < 2; ++mi)
#pragma unroll
            for (int ni = 0; ni < 4; ++ni) acc[mi][ni] = (f32x4){0.f, 0.f, 0.f, 0.f};

#pragma unroll
        for (int ks = 0; ks < 4; ++ks) {
#pragma unroll
            for (int ni = 0; ni < 4; ++ni) {
                acc[0][ni] = __builtin_amdgcn_mfma_f32_16x16x32_bf16(
                    u[ks * 2 + 0], Wf[ni][ks], acc[0][ni], 0, 0, 0);
                acc[1][ni] = __builtin_amdgcn_mfma_f32_16x16x32_bf16(
                    u[ks * 2 + 1], Wf[ni][ks], acc[1][ni], 0, 0, 0);
            }
        }

        float* ob = out + (size_t)(row0 + m0w) * NCOLS + g * GD + nh * 64;
#pragma unroll
        for (int mi = 0; mi < 2; ++mi)
#pragma unroll
            for (int ni = 0; ni < 4; ++ni)
#pragma unroll
                for (int r = 0; r < 4; ++r)
                    ob[(size_t)(mi * 16 + lk * 4 + r) * NCOLS + ni * 16 + lm]
                        = acc[mi][ni][r] - mw[ni];
    }
}

extern "C" void kernel_launch(void* const* d_in, const int* in_sizes, int n_in,
                              void* d_out, int out_size, void* d_ws, size_t ws_size,
                              hipStream_t stream) {
    const float* x = (const float*)d_in[0];
    float* out = (float*)d_out;
    float* ws = (float*)d_ws;

    float* xtx   = ws;                                    // 8,388,608 f
    float* ps    = xtx + (size_t)NG * NPC * GD * GD;      // 65,536 f
    float* mean  = ps + (size_t)NG * NPC * GD;            // 4,096
    float* scale = mean + NCOLS;                          // 32
    float* Cbuf  = scale + 32;                            // 524,288
    float* Ya    = Cbuf + (size_t)NG * GD * GD;
    float* Za    = Ya + (size_t)NG * GD * GD;
    float* Yb    = Za + (size_t)NG * GD * GD;
    float* Zb    = Yb + (size_t)NG * GD * GD;
    float* muW   = Zb + (size_t)NG * GD * GD;             // 4,096
    unsigned short* WT  = (unsigned short*)(muW + NCOLS); // 4 MB
    unsigned short* xhi = WT + (size_t)NG * GD * GD;      // 128 MB

    k_cov<<<NG * NPC, 256, 0, stream>>>(x, xtx, ps, xhi);
    k_mean<<<NCOLS / 256, 256, 0, stream>>>(ps, mean);
    k_covreduce<<<NG * NPC, 256, 0, stream>>>(xtx, mean, Cbuf);
    k_prep<<<NG, 256, 0, stream>>>(Cbuf, scale, Ya, Za);
    // 5 Newton-Schulz iterations (e0~0.19 -> e5 ~ 7e-14): final Z in Zb
    for (int it = 0; it < 5; ++it) {
        if ((it & 1) == 0)
            k_ns_iter<<<NG * 8, 256, 0, stream>>>(Ya, Za, Yb, Zb);
        else
            k_ns_iter<<<NG * 8, 256, 0, stream>>>(Yb, Zb, Ya, Za);
    }
    k_wprep<<<NG, 256, 0, stream>>>(Zb, scale, mean, WT, muW);
    k_apply<<<NG * 64, 256, 0, stream>>>(xhi, WT, muW, out);
}